// Round 7
// baseline (433.994 us; speedup 1.0000x reference)
//
#include <hip/hip_runtime.h>
#include <hip/hip_fp16.h>
#include <math.h>

// Problem constants (fixed by the reference)
constexpr int   N   = 50000;
constexpr int   E   = 600000;
constexpr int   FIN = 128;
constexpr int   H   = 64;
constexpr int   C   = 40;
constexpr int   K   = 10;
constexpr float CK  = (1.0f - 0.1f) / 10.0f;  // (1-alpha)/K
constexpr float AL  = 0.1f;                   // alpha

// round-to-nearest-even fp32 -> bf16 (returns low 16 bits)
__device__ __forceinline__ unsigned bf16_rne(float f) {
    unsigned u = __float_as_uint(f);
    return (u + 0x7fffu + ((u >> 16) & 1u)) >> 16;
}
__device__ __forceinline__ float bf16_lo(unsigned d) { return __uint_as_float(d << 16); }
__device__ __forceinline__ float bf16_hi(unsigned d) { return __uint_as_float(d & 0xffff0000u); }

// ---------------------------------------------------------------------------
// y0 = x @ W1   (N x 128) @ (128 x 64)
// 64 nodes/block, 256 threads; W1 + padded x rows in LDS; 4x4 register tile.
// ---------------------------------------------------------------------------
constexpr int G1N  = 64;
constexpr int XPAD = 132;
__global__ __launch_bounds__(256, 2) void k_gemm1(const float* __restrict__ x,
                                                  const float* __restrict__ W1,
                                                  float* __restrict__ y0,
                                                  unsigned short* __restrict__ y0b) {
    __shared__ float ws[FIN * H];
    __shared__ float xs[G1N * XPAD];
    const float4* W14 = (const float4*)W1;
    const float4* x4  = (const float4*)x;
    int t = threadIdx.x;
    int node0 = blockIdx.x * G1N;
    for (int i = t; i < FIN * H / 4; i += 256) ((float4*)ws)[i] = W14[i];
    for (int p = 0; p < 8; ++p) {
        int idx = p * 256 + t;
        int n   = idx >> 5;
        int kk  = idx & 31;
        int node = node0 + n;
        float4 v = (node < N) ? x4[(size_t)node * (FIN / 4) + kk]
                              : make_float4(0.f, 0.f, 0.f, 0.f);
        *(float4*)(xs + n * XPAD + kk * 4) = v;
    }
    __syncthreads();
    int nb = (t >> 4) * 4;
    int cb = (t & 15) * 4;
    float a00=0,a01=0,a02=0,a03=0, a10=0,a11=0,a12=0,a13=0;
    float a20=0,a21=0,a22=0,a23=0, a30=0,a31=0,a32=0,a33=0;
#pragma unroll 8
    for (int k = 0; k < FIN; ++k) {
        float4 wv = *(const float4*)(ws + k * H + cb);
        float x0 = xs[(nb + 0) * XPAD + k];
        float x1 = xs[(nb + 1) * XPAD + k];
        float x2 = xs[(nb + 2) * XPAD + k];
        float x3 = xs[(nb + 3) * XPAD + k];
        a00 = fmaf(x0, wv.x, a00); a01 = fmaf(x0, wv.y, a01);
        a02 = fmaf(x0, wv.z, a02); a03 = fmaf(x0, wv.w, a03);
        a10 = fmaf(x1, wv.x, a10); a11 = fmaf(x1, wv.y, a11);
        a12 = fmaf(x1, wv.z, a12); a13 = fmaf(x1, wv.w, a13);
        a20 = fmaf(x2, wv.x, a20); a21 = fmaf(x2, wv.y, a21);
        a22 = fmaf(x2, wv.z, a22); a23 = fmaf(x2, wv.w, a23);
        a30 = fmaf(x3, wv.x, a30); a31 = fmaf(x3, wv.y, a31);
        a32 = fmaf(x3, wv.z, a32); a33 = fmaf(x3, wv.w, a33);
    }
    float4 rows[4] = {make_float4(a00,a01,a02,a03), make_float4(a10,a11,a12,a13),
                      make_float4(a20,a21,a22,a23), make_float4(a30,a31,a32,a33)};
#pragma unroll
    for (int i = 0; i < 4; ++i) {
        int node = node0 + nb + i;
        if (node >= N) break;
        float4 r = rows[i];
        *(float4*)(y0 + (size_t)node * H + cb) = r;
        uint2 pb;
        pb.x = (bf16_rne(r.y) << 16) | bf16_rne(r.x);
        pb.y = (bf16_rne(r.w) << 16) | bf16_rne(r.z);
        *(uint2*)(y0b + (size_t)node * H + cb) = pb;
    }
}

// ---------------------------------------------------------------------------
// Per-row edge count, 8-way privatized to kill cross-XCD line ping-pong
// ---------------------------------------------------------------------------
__global__ void k_count(const int* __restrict__ row, int* __restrict__ cnt8) {
    int e = blockIdx.x * blockDim.x + threadIdx.x;
    if (e >= E) return;
    atomicAdd(&cnt8[(size_t)(blockIdx.x & 7) * N + row[e]], 1);
}

// ---------------------------------------------------------------------------
// Two-level exclusive scan of summed cnt8 -> row_ptr[]
// ---------------------------------------------------------------------------
__global__ __launch_bounds__(1024) void k_scan_blocks(const int* __restrict__ cnt8,
                                                      int* __restrict__ row_ptr,
                                                      int* __restrict__ bsum) {
    __shared__ int s[1024];
    int gid = blockIdx.x * 1024 + threadIdx.x;
    int v = 0;
    if (gid < N) {
#pragma unroll
        for (int c = 0; c < 8; ++c) v += cnt8[(size_t)c * N + gid];
    }
    s[threadIdx.x] = v;
    __syncthreads();
    for (int off = 1; off < 1024; off <<= 1) {
        int t = (threadIdx.x >= off) ? s[threadIdx.x - off] : 0;
        __syncthreads();
        s[threadIdx.x] += t;
        __syncthreads();
    }
    if (gid < N) row_ptr[gid] = s[threadIdx.x] - v;  // exclusive
    if (threadIdx.x == 1023) bsum[blockIdx.x] = s[1023];
}

__global__ void k_scan_sums(const int* __restrict__ bsum, int* __restrict__ boff, int nb) {
    int lane = threadIdx.x;
    int orig = (lane < nb) ? bsum[lane] : 0;
    int v = orig;
    for (int off = 1; off < 64; off <<= 1) {
        int t = __shfl_up(v, off, 64);
        if (lane >= off) v += t;
    }
    if (lane < nb) boff[lane] = v - orig;
}

__global__ __launch_bounds__(1024) void k_addoff(int* __restrict__ row_ptr,
                                                 const int* __restrict__ boff) {
    int gid = blockIdx.x * 1024 + threadIdx.x;
    if (gid < N) row_ptr[gid] += boff[blockIdx.x];
    if (gid == 0) row_ptr[N] = E;
}

// ---------------------------------------------------------------------------
// Scatter edges into CSR; raw (col, weight) per edge (8 B)
// ---------------------------------------------------------------------------
__global__ void k_scatter(const int* __restrict__ row, const int* __restrict__ col,
                          const float* __restrict__ w,
                          const int* __restrict__ row_ptr, int* __restrict__ fill,
                          int2* __restrict__ ep) {
    int e = blockIdx.x * blockDim.x + threadIdx.x;
    if (e >= E) return;
    int r = row[e];
    int p = row_ptr[r] + atomicAdd(&fill[r], 1);
    ep[p] = make_int2(col[e], __float_as_int(w[e]));
}

// ---------------------------------------------------------------------------
// Weighted degree from CSR rows + dinv/dinv2
// ---------------------------------------------------------------------------
__global__ void k_deg_dinv(const int2* __restrict__ ep, const int* __restrict__ row_ptr,
                           float* __restrict__ dinv, float* __restrict__ dinv2) {
    int i = blockIdx.x * blockDim.x + threadIdx.x;
    if (i >= N) return;
    float d = 1.0f;   // self-loop weight
    int e0 = row_ptr[i], e1 = row_ptr[i + 1];
    for (int j = e0; j < e1; ++j) d += __int_as_float(ep[j].y);
    float di = rsqrtf(d);
    dinv[i]  = di;
    dinv2[i] = di * di;
}

// ---------------------------------------------------------------------------
// Normalize edge weights in place: w <- dinv[r]*w*dinv[c]
// ---------------------------------------------------------------------------
__global__ __launch_bounds__(256) void k_norm(int2* __restrict__ ep,
                                              const int* __restrict__ row_ptr,
                                              const float* __restrict__ dinv) {
    int node = blockIdx.x * 32 + (threadIdx.x >> 3);
    if (node >= N) return;
    int l = threadIdx.x & 7;
    float dr = dinv[node];
    int e0 = row_ptr[node], e1 = row_ptr[node + 1];
    for (int j = e0 + l; j < e1; j += 8) {
        int2 v = ep[j];
        ep[j] = make_int2(v.x, __float_as_int(__int_as_float(v.y) * dr * dinv[v.x]));
    }
}

// ---------------------------------------------------------------------------
// Degree-bucket counting sort: perm[] groups nodes of equal (clamped) degree
// so each prop wave owns 8 similar-degree nodes (md ~= deg, no wasted iters).
// ---------------------------------------------------------------------------
__global__ __launch_bounds__(256) void k_hist(const int* __restrict__ row_ptr,
                                              int* __restrict__ hist) {
    __shared__ int lh[64];
    int t = threadIdx.x;
    if (t < 64) lh[t] = 0;
    __syncthreads();
    int i = blockIdx.x * 256 + t;
    if (i < N) {
        int d = min(row_ptr[i + 1] - row_ptr[i], 63);
        atomicAdd(&lh[d], 1);
    }
    __syncthreads();
    if (t < 64) atomicAdd(&hist[t], lh[t]);
}

__global__ void k_hist_scan(const int* __restrict__ hist, int* __restrict__ hbase) {
    int lane = threadIdx.x;   // 64 lanes
    int orig = hist[lane];
    int v = orig;
    for (int off = 1; off < 64; off <<= 1) {
        int t = __shfl_up(v, off, 64);
        if (lane >= off) v += t;
    }
    hbase[lane] = v - orig;   // exclusive
}

__global__ __launch_bounds__(256) void k_perm(const int* __restrict__ row_ptr,
                                              const int* __restrict__ hbase,
                                              int* __restrict__ hfill,   // 64 x 32-int padded
                                              int* __restrict__ perm) {
    int i = blockIdx.x * 256 + threadIdx.x;
    if (i >= N) return;
    int d = min(row_ptr[i + 1] - row_ptr[i], 63);
    int pos = hbase[d] + atomicAdd(&hfill[d * 32], 1);  // 128B-padded counters
    perm[pos] = i;
}

// ---------------------------------------------------------------------------
// One propagation hop. 8 nodes per wave (lane = node-sub x feature-octet),
// degree-sorted via perm, 4 edges in flight. 32 nodes/block.
// FINAL fuses the MLP epilogue.
// ---------------------------------------------------------------------------
template <bool WRITE_H, bool ACC_INIT, bool FINAL>
__global__ __launch_bounds__(256) void k_prop(const uint4* __restrict__ hin,   // N x (H/8)
                                              uint4* __restrict__ hout,
                                              __half* __restrict__ acch,       // N x H fp16
                                              const float* __restrict__ dinv2,
                                              const int* __restrict__ row_ptr,
                                              const int2* __restrict__ ep,
                                              const int* __restrict__ perm,
                                              const float4* __restrict__ y04,
                                              const float* __restrict__ b1,
                                              const float* __restrict__ W2,
                                              const float* __restrict__ b2,
                                              float* __restrict__ out) {
    __shared__ float w2s[H * C];   // used only when FINAL
    __shared__ float hs[32 * H];
    __shared__ float b2s[C];
    __shared__ float b1s[H];
    int t = threadIdx.x;
    if (FINAL) {
        for (int i = t; i < H * C; i += 256) w2s[i] = W2[i];
        if (t < C) b2s[t] = b2[t];
        if (t < H) b1s[t] = b1[t];
        __syncthreads();
    }
    int lane = t & 63;
    int nib  = (t >> 6) * 8 + (lane >> 3);   // node-in-block 0..31
    int l    = lane & 7;                     // feature octet
    int idx  = blockIdx.x * 32 + nib;
    bool nv  = idx < N;
    int node = perm[nv ? idx : N - 1];
    int start = row_ptr[node];
    int deg   = nv ? (row_ptr[node + 1] - start) : 0;
    int md = deg;                            // wave max degree
    md = max(md, __shfl_xor(md, 8, 64));
    md = max(md, __shfl_xor(md, 16, 64));
    md = max(md, __shfl_xor(md, 32, 64));
    float s0=0.f,s1=0.f,s2=0.f,s3=0.f,s4=0.f,s5=0.f,s6=0.f,s7=0.f;
    for (int j = 0; j < md; j += 4) {
        bool a0 = j < deg, a1 = j + 1 < deg, a2 = j + 2 < deg, a3 = j + 3 < deg;
        int2 e0 = ep[a0 ? start + j     : 0];
        int2 e1 = ep[a1 ? start + j + 1 : 0];
        int2 e2 = ep[a2 ? start + j + 2 : 0];
        int2 e3 = ep[a3 ? start + j + 3 : 0];
        uint4 v0 = hin[(size_t)e0.x * (H / 8) + l];
        uint4 v1 = hin[(size_t)e1.x * (H / 8) + l];
        uint4 v2 = hin[(size_t)e2.x * (H / 8) + l];
        uint4 v3 = hin[(size_t)e3.x * (H / 8) + l];
        float w0 = a0 ? __int_as_float(e0.y) : 0.0f;
        float w1 = a1 ? __int_as_float(e1.y) : 0.0f;
        float w2 = a2 ? __int_as_float(e2.y) : 0.0f;
        float w3 = a3 ? __int_as_float(e3.y) : 0.0f;
        s0 = fmaf(w0, bf16_lo(v0.x), s0); s1 = fmaf(w0, bf16_hi(v0.x), s1);
        s2 = fmaf(w0, bf16_lo(v0.y), s2); s3 = fmaf(w0, bf16_hi(v0.y), s3);
        s4 = fmaf(w0, bf16_lo(v0.z), s4); s5 = fmaf(w0, bf16_hi(v0.z), s5);
        s6 = fmaf(w0, bf16_lo(v0.w), s6); s7 = fmaf(w0, bf16_hi(v0.w), s7);
        s0 = fmaf(w1, bf16_lo(v1.x), s0); s1 = fmaf(w1, bf16_hi(v1.x), s1);
        s2 = fmaf(w1, bf16_lo(v1.y), s2); s3 = fmaf(w1, bf16_hi(v1.y), s3);
        s4 = fmaf(w1, bf16_lo(v1.z), s4); s5 = fmaf(w1, bf16_hi(v1.z), s5);
        s6 = fmaf(w1, bf16_lo(v1.w), s6); s7 = fmaf(w1, bf16_hi(v1.w), s7);
        s0 = fmaf(w2, bf16_lo(v2.x), s0); s1 = fmaf(w2, bf16_hi(v2.x), s1);
        s2 = fmaf(w2, bf16_lo(v2.y), s2); s3 = fmaf(w2, bf16_hi(v2.y), s3);
        s4 = fmaf(w2, bf16_lo(v2.z), s4); s5 = fmaf(w2, bf16_hi(v2.z), s5);
        s6 = fmaf(w2, bf16_lo(v2.w), s6); s7 = fmaf(w2, bf16_hi(v2.w), s7);
        s0 = fmaf(w3, bf16_lo(v3.x), s0); s1 = fmaf(w3, bf16_hi(v3.x), s1);
        s2 = fmaf(w3, bf16_lo(v3.y), s2); s3 = fmaf(w3, bf16_hi(v3.y), s3);
        s4 = fmaf(w3, bf16_lo(v3.z), s4); s5 = fmaf(w3, bf16_hi(v3.z), s5);
        s6 = fmaf(w3, bf16_lo(v3.w), s6); s7 = fmaf(w3, bf16_hi(v3.w), s7);
    }
    if (nv) {
        size_t base = (size_t)node * (H / 8) + l;
        float d2 = dinv2[node];
        uint4 hv = hin[base];              // self-loop term
        s0 = fmaf(d2, bf16_lo(hv.x), s0); s1 = fmaf(d2, bf16_hi(hv.x), s1);
        s2 = fmaf(d2, bf16_lo(hv.y), s2); s3 = fmaf(d2, bf16_hi(hv.y), s3);
        s4 = fmaf(d2, bf16_lo(hv.z), s4); s5 = fmaf(d2, bf16_hi(hv.z), s5);
        s6 = fmaf(d2, bf16_lo(hv.w), s6); s7 = fmaf(d2, bf16_hi(hv.w), s7);
        if (WRITE_H) {
            uint4 o;
            o.x = (bf16_rne(s1) << 16) | bf16_rne(s0);
            o.y = (bf16_rne(s3) << 16) | bf16_rne(s2);
            o.z = (bf16_rne(s5) << 16) | bf16_rne(s4);
            o.w = (bf16_rne(s7) << 16) | bf16_rne(s6);
            hout[base] = o;
        }
        uint4* ap = (uint4*)(acch + (size_t)node * H + l * 8);
        if (FINAL) {
            uint4 old = *ap;               // acc of hops 0..K-2
            float2 f;
            f = __half22float2(*(__half2*)&old.x); s0 += f.x; s1 += f.y;
            f = __half22float2(*(__half2*)&old.y); s2 += f.x; s3 += f.y;
            f = __half22float2(*(__half2*)&old.z); s4 += f.x; s5 += f.y;
            f = __half22float2(*(__half2*)&old.w); s6 += f.x; s7 += f.y;
            float4 ya = y04[(size_t)node * (H / 4) + 2 * l];
            float4 yb = y04[(size_t)node * (H / 4) + 2 * l + 1];
            const float* bp = b1s + l * 8;
            float* hp = hs + nib * H + l * 8;
            hp[0] = fmaxf(fmaf(CK, s0, fmaf(AL, ya.x, bp[0])), 0.f);
            hp[1] = fmaxf(fmaf(CK, s1, fmaf(AL, ya.y, bp[1])), 0.f);
            hp[2] = fmaxf(fmaf(CK, s2, fmaf(AL, ya.z, bp[2])), 0.f);
            hp[3] = fmaxf(fmaf(CK, s3, fmaf(AL, ya.w, bp[3])), 0.f);
            hp[4] = fmaxf(fmaf(CK, s4, fmaf(AL, yb.x, bp[4])), 0.f);
            hp[5] = fmaxf(fmaf(CK, s5, fmaf(AL, yb.y, bp[5])), 0.f);
            hp[6] = fmaxf(fmaf(CK, s6, fmaf(AL, yb.z, bp[6])), 0.f);
            hp[7] = fmaxf(fmaf(CK, s7, fmaf(AL, yb.w, bp[7])), 0.f);
        } else {
            if (!ACC_INIT) {
                uint4 old = *ap;
                float2 f;
                f = __half22float2(*(__half2*)&old.x); s0 += f.x; s1 += f.y;
                f = __half22float2(*(__half2*)&old.y); s2 += f.x; s3 += f.y;
                f = __half22float2(*(__half2*)&old.z); s4 += f.x; s5 += f.y;
                f = __half22float2(*(__half2*)&old.w); s6 += f.x; s7 += f.y;
            }
            uint4 nvp;
            __half2 h;
            h = __floats2half2_rn(s0, s1); nvp.x = *(unsigned*)&h;
            h = __floats2half2_rn(s2, s3); nvp.y = *(unsigned*)&h;
            h = __floats2half2_rn(s4, s5); nvp.z = *(unsigned*)&h;
            h = __floats2half2_rn(s6, s7); nvp.w = *(unsigned*)&h;
            *ap = nvp;
        }
    }
    if (FINAL) {
        __syncthreads();
        int idx0 = blockIdx.x * 32;
        for (int o = t; o < 32 * C; o += 256) {
            int nl = o / C, c = o % C;
            int i2 = idx0 + nl;
            if (i2 >= N) continue;
            int n2 = perm[i2];
            float s = b2s[c];
            const float* hr = &hs[nl * H];
#pragma unroll
            for (int k = 0; k < H; ++k) s = fmaf(hr[k], w2s[k * C + c], s);
            out[n2 * C + c] = s;
        }
    }
}

// ---------------------------------------------------------------------------
extern "C" void kernel_launch(void* const* d_in, const int* in_sizes, int n_in,
                              void* d_out, int out_size, void* d_ws, size_t ws_size,
                              hipStream_t stream) {
    const float* x  = (const float*)d_in[0];
    const int*   ei = (const int*)d_in[1];
    const float* ew = (const float*)d_in[2];
    const float* W1 = (const float*)d_in[3];
    const float* b1 = (const float*)d_in[4];
    const float* W2 = (const float*)d_in[5];
    const float* b2 = (const float*)d_in[6];
    float* out = (float*)d_out;

    const int* row = ei;        // edge_index[0]
    const int* col = ei + E;    // edge_index[1]

    char* ws = (char*)d_ws;
    size_t off = 0;
    auto alloc = [&](size_t bytes) -> char* {
        char* p = ws + off;
        off = (off + bytes + 1023) & ~(size_t)1023;
        return p;
    };
    float*          y0  = (float*)alloc((size_t)N * H * 4);
    unsigned short* y0b = (unsigned short*)alloc((size_t)N * H * 2);
    unsigned short* ha  = (unsigned short*)alloc((size_t)N * H * 2);
    unsigned short* hb  = (unsigned short*)alloc((size_t)N * H * 2);
    __half*         acch= (__half*)alloc((size_t)N * H * 2);
    int*   cnt8   = (int*)  alloc((size_t)8 * N * 4);  // zeroed
    int*   fill   = (int*)  alloc((size_t)N * 4);      // zeroed
    int*   hist   = (int*)  alloc(64 * 4);             // zeroed
    int*   hfill  = (int*)  alloc(64 * 32 * 4);        // zeroed (128B-padded)
    float* dinv   = (float*)alloc((size_t)N * 4);
    float* dinv2  = (float*)alloc((size_t)N * 4);
    int*   row_ptr= (int*)  alloc((size_t)(N + 1) * 4);
    int*   bsum   = (int*)  alloc(64 * 4);
    int*   boff   = (int*)  alloc(64 * 4);
    int*   hbase  = (int*)  alloc(64 * 4);
    int*   perm   = (int*)  alloc((size_t)N * 4);
    int2*  ep     = (int2*) alloc((size_t)E * 8);

    // zero cnt8|fill|hist|hfill (contiguous in bump order)
    hipMemsetAsync(cnt8, 0, (size_t)((char*)dinv - (char*)cnt8), stream);

    // 1) y0 = x @ W1 (fp32 out + bf16 out)
    k_gemm1<<<(N + G1N - 1) / G1N, 256, 0, stream>>>(x, W1, y0, y0b);

    // 2) per-row edge counts (privatized)
    k_count<<<(E + 255) / 256, 256, 0, stream>>>(row, cnt8);

    // 3) scan counts -> row_ptr
    constexpr int NB = (N + 1023) / 1024;  // 49
    k_scan_blocks<<<NB, 1024, 0, stream>>>(cnt8, row_ptr, bsum);
    k_scan_sums<<<1, 64, 0, stream>>>(bsum, boff, NB);
    k_addoff<<<NB, 1024, 0, stream>>>(row_ptr, boff);

    // 4) CSR scatter, weighted degree + dinv, normalize in place
    k_scatter<<<(E + 255) / 256, 256, 0, stream>>>(row, col, ew, row_ptr, fill, ep);
    k_deg_dinv<<<(N + 255) / 256, 256, 0, stream>>>(ep, row_ptr, dinv, dinv2);
    k_norm<<<(N + 31) / 32, 256, 0, stream>>>(ep, row_ptr, dinv);

    // 4b) degree-bucket permutation
    k_hist<<<(N + 255) / 256, 256, 0, stream>>>(row_ptr, hist);
    k_hist_scan<<<1, 64, 0, stream>>>(hist, hbase);
    k_perm<<<(N + 255) / 256, 256, 0, stream>>>(row_ptr, hbase, hfill, perm);

    // 5) K hops; hop 0 inits acc, hop K-1 fuses the MLP epilogue
    const uint4* hin = (const uint4*)y0b;
    uint4* bufs[2] = {(uint4*)ha, (uint4*)hb};
    int grid = (N + 31) / 32;   // 1563 blocks, 32 nodes/block
    for (int hop = 0; hop < K; ++hop) {
        uint4* hout = bufs[hop & 1];
        if (hop == 0)
            k_prop<true, true, false><<<grid, 256, 0, stream>>>(hin, hout, acch, dinv2,
                row_ptr, ep, perm, (const float4*)y0, b1, W2, b2, out);
        else if (hop == K - 1)
            k_prop<false, false, true><<<grid, 256, 0, stream>>>(hin, hout, acch, dinv2,
                row_ptr, ep, perm, (const float4*)y0, b1, W2, b2, out);
        else
            k_prop<true, false, false><<<grid, 256, 0, stream>>>(hin, hout, acch, dinv2,
                row_ptr, ep, perm, (const float4*)y0, b1, W2, b2, out);
        hin = hout;
    }
}

// Round 8
// 355.049 us; speedup vs baseline: 1.2224x; 1.2224x over previous
//
#include <hip/hip_runtime.h>
#include <hip/hip_fp16.h>
#include <math.h>

// Problem constants (fixed by the reference)
constexpr int   N   = 50000;
constexpr int   E   = 600000;
constexpr int   FIN = 128;
constexpr int   H   = 64;
constexpr int   C   = 40;
constexpr int   K   = 10;
constexpr float CK  = (1.0f - 0.1f) / 10.0f;  // (1-alpha)/K
constexpr float AL  = 0.1f;                   // alpha

typedef float v2f __attribute__((ext_vector_type(2)));

// pack 4 fp32 -> 4 fp8 e4m3 (HW RNE, OCP on gfx950)
__device__ __forceinline__ unsigned pack_fp8x4(float f0, float f1, float f2, float f3) {
    unsigned r = __builtin_amdgcn_cvt_pk_fp8_f32(f0, f1, 0u, false);
    r = __builtin_amdgcn_cvt_pk_fp8_f32(f2, f3, r, true);
    return r;
}

// ---------------------------------------------------------------------------
// y0 = x @ W1   (N x 128) @ (128 x 64)
// 64 nodes/block, 256 threads; W1 + padded x rows in LDS; 4x4 register tile.
// Writes y0 fp32 (epilogue) + y0f8 fp8 (hop-0 gather input).
// ---------------------------------------------------------------------------
constexpr int G1N  = 64;
constexpr int XPAD = 132;
__global__ __launch_bounds__(256, 2) void k_gemm1(const float* __restrict__ x,
                                                  const float* __restrict__ W1,
                                                  float* __restrict__ y0,
                                                  unsigned char* __restrict__ y0f8) {
    __shared__ float ws[FIN * H];
    __shared__ float xs[G1N * XPAD];
    const float4* W14 = (const float4*)W1;
    const float4* x4  = (const float4*)x;
    int t = threadIdx.x;
    int node0 = blockIdx.x * G1N;
    for (int i = t; i < FIN * H / 4; i += 256) ((float4*)ws)[i] = W14[i];
    for (int p = 0; p < 8; ++p) {
        int idx = p * 256 + t;
        int n   = idx >> 5;
        int kk  = idx & 31;
        int node = node0 + n;
        float4 v = (node < N) ? x4[(size_t)node * (FIN / 4) + kk]
                              : make_float4(0.f, 0.f, 0.f, 0.f);
        *(float4*)(xs + n * XPAD + kk * 4) = v;
    }
    __syncthreads();
    int nb = (t >> 4) * 4;
    int cb = (t & 15) * 4;
    float a00=0,a01=0,a02=0,a03=0, a10=0,a11=0,a12=0,a13=0;
    float a20=0,a21=0,a22=0,a23=0, a30=0,a31=0,a32=0,a33=0;
#pragma unroll 8
    for (int k = 0; k < FIN; ++k) {
        float4 wv = *(const float4*)(ws + k * H + cb);
        float x0 = xs[(nb + 0) * XPAD + k];
        float x1 = xs[(nb + 1) * XPAD + k];
        float x2 = xs[(nb + 2) * XPAD + k];
        float x3 = xs[(nb + 3) * XPAD + k];
        a00 = fmaf(x0, wv.x, a00); a01 = fmaf(x0, wv.y, a01);
        a02 = fmaf(x0, wv.z, a02); a03 = fmaf(x0, wv.w, a03);
        a10 = fmaf(x1, wv.x, a10); a11 = fmaf(x1, wv.y, a11);
        a12 = fmaf(x1, wv.z, a12); a13 = fmaf(x1, wv.w, a13);
        a20 = fmaf(x2, wv.x, a20); a21 = fmaf(x2, wv.y, a21);
        a22 = fmaf(x2, wv.z, a22); a23 = fmaf(x2, wv.w, a23);
        a30 = fmaf(x3, wv.x, a30); a31 = fmaf(x3, wv.y, a31);
        a32 = fmaf(x3, wv.z, a32); a33 = fmaf(x3, wv.w, a33);
    }
    float4 rows[4] = {make_float4(a00,a01,a02,a03), make_float4(a10,a11,a12,a13),
                      make_float4(a20,a21,a22,a23), make_float4(a30,a31,a32,a33)};
#pragma unroll
    for (int i = 0; i < 4; ++i) {
        int node = node0 + nb + i;
        if (node >= N) break;
        float4 r = rows[i];
        *(float4*)(y0 + (size_t)node * H + cb) = r;
        *(unsigned*)(y0f8 + (size_t)node * H + cb) = pack_fp8x4(r.x, r.y, r.z, r.w);
    }
}

// ---------------------------------------------------------------------------
// Per-row edge count, 8-way privatized (blockIdx&7 ~ XCD id -> local atomics)
// ---------------------------------------------------------------------------
__global__ void k_count(const int* __restrict__ row, int* __restrict__ cnt8) {
    int e = blockIdx.x * blockDim.x + threadIdx.x;
    if (e >= E) return;
    atomicAdd(&cnt8[(size_t)(blockIdx.x & 7) * N + row[e]], 1);
}

// ---------------------------------------------------------------------------
// Two-level exclusive scan of summed cnt8 -> row_ptr[]
// ---------------------------------------------------------------------------
__global__ __launch_bounds__(1024) void k_scan_blocks(const int* __restrict__ cnt8,
                                                      int* __restrict__ row_ptr,
                                                      int* __restrict__ bsum) {
    __shared__ int s[1024];
    int gid = blockIdx.x * 1024 + threadIdx.x;
    int v = 0;
    if (gid < N) {
#pragma unroll
        for (int c = 0; c < 8; ++c) v += cnt8[(size_t)c * N + gid];
    }
    s[threadIdx.x] = v;
    __syncthreads();
    for (int off = 1; off < 1024; off <<= 1) {
        int t = (threadIdx.x >= off) ? s[threadIdx.x - off] : 0;
        __syncthreads();
        s[threadIdx.x] += t;
        __syncthreads();
    }
    if (gid < N) row_ptr[gid] = s[threadIdx.x] - v;  // exclusive
    if (threadIdx.x == 1023) bsum[blockIdx.x] = s[1023];
}

__global__ void k_scan_sums(const int* __restrict__ bsum, int* __restrict__ boff, int nb) {
    int lane = threadIdx.x;
    int orig = (lane < nb) ? bsum[lane] : 0;
    int v = orig;
    for (int off = 1; off < 64; off <<= 1) {
        int t = __shfl_up(v, off, 64);
        if (lane >= off) v += t;
    }
    if (lane < nb) boff[lane] = v - orig;
}

__global__ __launch_bounds__(1024) void k_addoff(int* __restrict__ row_ptr,
                                                 const int* __restrict__ boff) {
    int gid = blockIdx.x * 1024 + threadIdx.x;
    if (gid < N) row_ptr[gid] += boff[blockIdx.x];
    if (gid == 0) row_ptr[N] = E;
}

// ---------------------------------------------------------------------------
// Turn cnt8 copies into per-copy scatter base offsets:
// cnt8[c][r] <- row_ptr[r] + sum_{c'<c} cnt8[c'][r]
// ---------------------------------------------------------------------------
__global__ void k_mkoff(const int* __restrict__ row_ptr, int* __restrict__ cnt8) {
    int i = blockIdx.x * blockDim.x + threadIdx.x;
    if (i >= N) return;
    int off = row_ptr[i];
#pragma unroll
    for (int c = 0; c < 8; ++c) {
        int t = cnt8[(size_t)c * N + i];
        cnt8[(size_t)c * N + i] = off;
        off += t;
    }
}

// ---------------------------------------------------------------------------
// Scatter edges into CSR; atomics only within the XCD-private copy.
// Grid/mapping identical to k_count so capacities match.
// ---------------------------------------------------------------------------
__global__ void k_scatter(const int* __restrict__ row, const int* __restrict__ col,
                          const float* __restrict__ w,
                          int* __restrict__ off8, int2* __restrict__ ep) {
    int e = blockIdx.x * blockDim.x + threadIdx.x;
    if (e >= E) return;
    int r = row[e];
    int p = atomicAdd(&off8[(size_t)(blockIdx.x & 7) * N + r], 1);
    ep[p] = make_int2(col[e], __float_as_int(w[e]));
}

// ---------------------------------------------------------------------------
// Weighted degree from CSR rows + dinv/dinv2
// ---------------------------------------------------------------------------
__global__ void k_deg_dinv(const int2* __restrict__ ep, const int* __restrict__ row_ptr,
                           float* __restrict__ dinv, float* __restrict__ dinv2) {
    int i = blockIdx.x * blockDim.x + threadIdx.x;
    if (i >= N) return;
    float d = 1.0f;   // self-loop weight
    int e0 = row_ptr[i], e1 = row_ptr[i + 1];
    for (int j = e0; j < e1; ++j) d += __int_as_float(ep[j].y);
    float di = rsqrtf(d);
    dinv[i]  = di;
    dinv2[i] = di * di;
}

// ---------------------------------------------------------------------------
// Normalize edge weights in place: w <- dinv[r]*w*dinv[c]
// ---------------------------------------------------------------------------
__global__ __launch_bounds__(256) void k_norm(int2* __restrict__ ep,
                                              const int* __restrict__ row_ptr,
                                              const float* __restrict__ dinv) {
    int node = blockIdx.x * 32 + (threadIdx.x >> 3);
    if (node >= N) return;
    int l = threadIdx.x & 7;
    float dr = dinv[node];
    int e0 = row_ptr[node], e1 = row_ptr[node + 1];
    for (int j = e0 + l; j < e1; j += 8) {
        int2 v = ep[j];
        ep[j] = make_int2(v.x, __float_as_int(__int_as_float(v.y) * dr * dinv[v.x]));
    }
}

// ---------------------------------------------------------------------------
// One propagation hop, fp8 h storage (64 B row = ONE cache line per edge).
// 16 nodes per wave: lane = (node-sub 0..15) x (feature-16-group 0..3).
// 64 nodes/block. acc fp16. FINAL fuses the MLP epilogue (dynamic LDS).
// ---------------------------------------------------------------------------
template <bool WRITE_H, bool ACC_INIT, bool FINAL>
__global__ __launch_bounds__(256) void k_prop(const uint4* __restrict__ hin,   // N x 4 (fp8x16)
                                              uint4* __restrict__ hout,
                                              __half* __restrict__ acch,       // N x H fp16
                                              const float* __restrict__ dinv2,
                                              const int* __restrict__ row_ptr,
                                              const int2* __restrict__ ep,
                                              const float4* __restrict__ y04,
                                              const float* __restrict__ b1,
                                              const float* __restrict__ W2,
                                              const float* __restrict__ b2,
                                              float* __restrict__ out) {
    extern __shared__ float smem[];          // FINAL only: w2s | hs | b2s | b1s
    float* w2s = smem;
    float* hs  = smem + H * C;
    float* b2s = hs + 64 * H;
    float* b1s = b2s + C;
    int t = threadIdx.x;
    if (FINAL) {
        for (int i = t; i < H * C; i += 256) w2s[i] = W2[i];
        if (t < C) b2s[t] = b2[t];
        if (t < H) b1s[t] = b1[t];
        __syncthreads();
    }
    int lane = t & 63;
    int nib  = (t >> 6) * 16 + (lane >> 2);  // node-in-block 0..63
    int l    = lane & 3;                     // feature 16-group
    int node = blockIdx.x * 64 + nib;
    bool nv  = node < N;
    int nodec = nv ? node : N - 1;
    int start = row_ptr[nodec];
    int deg   = nv ? (row_ptr[nodec + 1] - start) : 0;
    int md = deg;                            // max degree across the wave's 16 nodes
    md = max(md, __shfl_xor(md, 4, 64));
    md = max(md, __shfl_xor(md, 8, 64));
    md = max(md, __shfl_xor(md, 16, 64));
    md = max(md, __shfl_xor(md, 32, 64));
    float s[16];
#pragma unroll
    for (int i = 0; i < 16; ++i) s[i] = 0.0f;
    auto accum = [&](uint4 v, float w) {
        const unsigned* dw = (const unsigned*)&v;
#pragma unroll
        for (int d = 0; d < 4; ++d) {
            v2f a = __builtin_amdgcn_cvt_pk_f32_fp8(dw[d], false);
            v2f b = __builtin_amdgcn_cvt_pk_f32_fp8(dw[d], true);
            s[4*d+0] = fmaf(w, a.x, s[4*d+0]);
            s[4*d+1] = fmaf(w, a.y, s[4*d+1]);
            s[4*d+2] = fmaf(w, b.x, s[4*d+2]);
            s[4*d+3] = fmaf(w, b.y, s[4*d+3]);
        }
    };
    for (int j = 0; j < md; j += 2) {
        bool a0 = j < deg, a1 = j + 1 < deg;
        int2 e0 = ep[a0 ? start + j     : 0];
        int2 e1 = ep[a1 ? start + j + 1 : 0];
        uint4 v0 = hin[(size_t)e0.x * 4 + l];
        uint4 v1 = hin[(size_t)e1.x * 4 + l];
        float w0 = a0 ? __int_as_float(e0.y) : 0.0f;
        float w1 = a1 ? __int_as_float(e1.y) : 0.0f;
        accum(v0, w0);
        accum(v1, w1);
    }
    if (nv) {
        size_t base = (size_t)node * 4 + l;
        accum(hin[base], dinv2[node]);       // self-loop term
        if (WRITE_H) {
            uint4 o;
            o.x = pack_fp8x4(s[0],  s[1],  s[2],  s[3]);
            o.y = pack_fp8x4(s[4],  s[5],  s[6],  s[7]);
            o.z = pack_fp8x4(s[8],  s[9],  s[10], s[11]);
            o.w = pack_fp8x4(s[12], s[13], s[14], s[15]);
            hout[base] = o;
        }
        uint4* ap = (uint4*)(acch + (size_t)node * H + l * 16);   // 2 x uint4
        if (FINAL) {
            uint4 o0 = ap[0], o1 = ap[1];
            const unsigned* u0 = (const unsigned*)&o0;
            const unsigned* u1 = (const unsigned*)&o1;
#pragma unroll
            for (int d = 0; d < 4; ++d) {
                float2 f0 = __half22float2(*(__half2*)&u0[d]);
                float2 f1 = __half22float2(*(__half2*)&u1[d]);
                s[2*d+0] += f0.x; s[2*d+1] += f0.y;
                s[8+2*d+0] += f1.x; s[8+2*d+1] += f1.y;
            }
            const float* bp = b1s + l * 16;
            float* hp = hs + nib * H + l * 16;
#pragma unroll
            for (int q = 0; q < 4; ++q) {
                float4 y = y04[(size_t)node * (H / 4) + l * 4 + q];
                hp[4*q+0] = fmaxf(fmaf(CK, s[4*q+0], fmaf(AL, y.x, bp[4*q+0])), 0.f);
                hp[4*q+1] = fmaxf(fmaf(CK, s[4*q+1], fmaf(AL, y.y, bp[4*q+1])), 0.f);
                hp[4*q+2] = fmaxf(fmaf(CK, s[4*q+2], fmaf(AL, y.z, bp[4*q+2])), 0.f);
                hp[4*q+3] = fmaxf(fmaf(CK, s[4*q+3], fmaf(AL, y.w, bp[4*q+3])), 0.f);
            }
        } else {
            if (!ACC_INIT) {
                uint4 o0 = ap[0], o1 = ap[1];
                const unsigned* u0 = (const unsigned*)&o0;
                const unsigned* u1 = (const unsigned*)&o1;
#pragma unroll
                for (int d = 0; d < 4; ++d) {
                    float2 f0 = __half22float2(*(__half2*)&u0[d]);
                    float2 f1 = __half22float2(*(__half2*)&u1[d]);
                    s[2*d+0] += f0.x; s[2*d+1] += f0.y;
                    s[8+2*d+0] += f1.x; s[8+2*d+1] += f1.y;
                }
            }
            uint4 n0, n1;
            unsigned* u0 = (unsigned*)&n0;
            unsigned* u1 = (unsigned*)&n1;
#pragma unroll
            for (int d = 0; d < 4; ++d) {
                __half2 h0 = __floats2half2_rn(s[2*d+0], s[2*d+1]);
                __half2 h1 = __floats2half2_rn(s[8+2*d+0], s[8+2*d+1]);
                u0[d] = *(unsigned*)&h0;
                u1[d] = *(unsigned*)&h1;
            }
            ap[0] = n0;
            ap[1] = n1;
        }
    }
    if (FINAL) {
        __syncthreads();
        int node0 = blockIdx.x * 64;
        for (int o = t; o < 64 * C; o += 256) {
            int nl = o / C, c = o % C;
            int n2 = node0 + nl;
            if (n2 >= N) continue;
            float v = b2s[c];
            const float* hr = &hs[nl * H];
#pragma unroll
            for (int k = 0; k < H; ++k) v = fmaf(hr[k], w2s[k * C + c], v);
            out[n2 * C + c] = v;
        }
    }
}

// ---------------------------------------------------------------------------
extern "C" void kernel_launch(void* const* d_in, const int* in_sizes, int n_in,
                              void* d_out, int out_size, void* d_ws, size_t ws_size,
                              hipStream_t stream) {
    const float* x  = (const float*)d_in[0];
    const int*   ei = (const int*)d_in[1];
    const float* ew = (const float*)d_in[2];
    const float* W1 = (const float*)d_in[3];
    const float* b1 = (const float*)d_in[4];
    const float* W2 = (const float*)d_in[5];
    const float* b2 = (const float*)d_in[6];
    float* out = (float*)d_out;

    const int* row = ei;        // edge_index[0]
    const int* col = ei + E;    // edge_index[1]

    char* ws = (char*)d_ws;
    size_t off = 0;
    auto alloc = [&](size_t bytes) -> char* {
        char* p = ws + off;
        off = (off + bytes + 1023) & ~(size_t)1023;
        return p;
    };
    float*         y0   = (float*)alloc((size_t)N * H * 4);
    unsigned char* y0f8 = (unsigned char*)alloc((size_t)N * H);
    unsigned char* ha   = (unsigned char*)alloc((size_t)N * H);
    unsigned char* hb   = (unsigned char*)alloc((size_t)N * H);
    __half*        acch = (__half*)alloc((size_t)N * H * 2);
    int*   cnt8   = (int*)  alloc((size_t)8 * N * 4);  // zeroed
    float* dinv   = (float*)alloc((size_t)N * 4);
    float* dinv2  = (float*)alloc((size_t)N * 4);
    int*   row_ptr= (int*)  alloc((size_t)(N + 1) * 4);
    int*   bsum   = (int*)  alloc(64 * 4);
    int*   boff   = (int*)  alloc(64 * 4);
    int2*  ep     = (int2*) alloc((size_t)E * 8);

    hipMemsetAsync(cnt8, 0, (size_t)8 * N * 4, stream);

    // 1) y0 = x @ W1 (fp32 + fp8)
    k_gemm1<<<(N + G1N - 1) / G1N, 256, 0, stream>>>(x, W1, y0, y0f8);

    // 2) per-row edge counts (XCD-privatized)
    k_count<<<(E + 255) / 256, 256, 0, stream>>>(row, cnt8);

    // 3) scan counts -> row_ptr; build per-copy scatter offsets
    constexpr int NB = (N + 1023) / 1024;  // 49
    k_scan_blocks<<<NB, 1024, 0, stream>>>(cnt8, row_ptr, bsum);
    k_scan_sums<<<1, 64, 0, stream>>>(bsum, boff, NB);
    k_addoff<<<NB, 1024, 0, stream>>>(row_ptr, boff);
    k_mkoff<<<(N + 255) / 256, 256, 0, stream>>>(row_ptr, cnt8);

    // 4) CSR scatter (XCD-private atomics), weighted degree + dinv, normalize
    k_scatter<<<(E + 255) / 256, 256, 0, stream>>>(row, col, ew, cnt8, ep);
    k_deg_dinv<<<(N + 255) / 256, 256, 0, stream>>>(ep, row_ptr, dinv, dinv2);
    k_norm<<<(N + 31) / 32, 256, 0, stream>>>(ep, row_ptr, dinv);

    // 5) K hops; hop 0 inits acc, hop K-1 fuses the MLP epilogue
    const uint4* hin = (const uint4*)y0f8;
    uint4* bufs[2] = {(uint4*)ha, (uint4*)hb};
    int grid = (N + 63) / 64;   // 782 blocks, 64 nodes/block
    size_t smemF = (size_t)(H * C + 64 * H + C + H) * 4;
    for (int hop = 0; hop < K; ++hop) {
        uint4* hout = bufs[hop & 1];
        if (hop == 0)
            k_prop<true, true, false><<<grid, 256, 0, stream>>>(hin, hout, acch, dinv2,
                row_ptr, ep, (const float4*)y0, b1, W2, b2, out);
        else if (hop == K - 1)
            k_prop<false, false, true><<<grid, 256, smemF, stream>>>(hin, hout, acch, dinv2,
                row_ptr, ep, (const float4*)y0, b1, W2, b2, out);
        else
            k_prop<true, false, false><<<grid, 256, 0, stream>>>(hin, hout, acch, dinv2,
                row_ptr, ep, (const float4*)y0, b1, W2, b2, out);
        hin = hout;
    }
}

// Round 9
// 343.355 us; speedup vs baseline: 1.2640x; 1.0341x over previous
//
#include <hip/hip_runtime.h>
#include <hip/hip_fp16.h>
#include <math.h>

// Problem constants (fixed by the reference)
constexpr int   N   = 50000;
constexpr int   E   = 600000;
constexpr int   FIN = 128;
constexpr int   H   = 64;
constexpr int   C   = 40;
constexpr int   K   = 10;
constexpr float CK  = (1.0f - 0.1f) / 10.0f;  // (1-alpha)/K
constexpr float AL  = 0.1f;                   // alpha

typedef float v2f __attribute__((ext_vector_type(2)));

// pack 4 fp32 -> 4 fp8 e4m3 (HW RNE, OCP on gfx950)
__device__ __forceinline__ unsigned pack_fp8x4(float f0, float f1, float f2, float f3) {
    unsigned r = __builtin_amdgcn_cvt_pk_fp8_f32(f0, f1, 0u, false);
    r = __builtin_amdgcn_cvt_pk_fp8_f32(f2, f3, r, true);
    return r;
}

// ---------------------------------------------------------------------------
// y0 = x @ W1   (N x 128) @ (128 x 64)
// 64 nodes/block, 256 threads; W1 + padded x rows in LDS; 4x4 register tile.
// Writes y0 fp32 (epilogue) + y0f8 fp8 (hop-0 gather input).
// ---------------------------------------------------------------------------
constexpr int G1N  = 64;
constexpr int XPAD = 132;
__global__ __launch_bounds__(256, 2) void k_gemm1(const float* __restrict__ x,
                                                  const float* __restrict__ W1,
                                                  float* __restrict__ y0,
                                                  unsigned char* __restrict__ y0f8) {
    __shared__ float ws[FIN * H];
    __shared__ float xs[G1N * XPAD];
    const float4* W14 = (const float4*)W1;
    const float4* x4  = (const float4*)x;
    int t = threadIdx.x;
    int node0 = blockIdx.x * G1N;
    for (int i = t; i < FIN * H / 4; i += 256) ((float4*)ws)[i] = W14[i];
    for (int p = 0; p < 8; ++p) {
        int idx = p * 256 + t;
        int n   = idx >> 5;
        int kk  = idx & 31;
        int node = node0 + n;
        float4 v = (node < N) ? x4[(size_t)node * (FIN / 4) + kk]
                              : make_float4(0.f, 0.f, 0.f, 0.f);
        *(float4*)(xs + n * XPAD + kk * 4) = v;
    }
    __syncthreads();
    int nb = (t >> 4) * 4;
    int cb = (t & 15) * 4;
    float a00=0,a01=0,a02=0,a03=0, a10=0,a11=0,a12=0,a13=0;
    float a20=0,a21=0,a22=0,a23=0, a30=0,a31=0,a32=0,a33=0;
#pragma unroll 8
    for (int k = 0; k < FIN; ++k) {
        float4 wv = *(const float4*)(ws + k * H + cb);
        float x0 = xs[(nb + 0) * XPAD + k];
        float x1 = xs[(nb + 1) * XPAD + k];
        float x2 = xs[(nb + 2) * XPAD + k];
        float x3 = xs[(nb + 3) * XPAD + k];
        a00 = fmaf(x0, wv.x, a00); a01 = fmaf(x0, wv.y, a01);
        a02 = fmaf(x0, wv.z, a02); a03 = fmaf(x0, wv.w, a03);
        a10 = fmaf(x1, wv.x, a10); a11 = fmaf(x1, wv.y, a11);
        a12 = fmaf(x1, wv.z, a12); a13 = fmaf(x1, wv.w, a13);
        a20 = fmaf(x2, wv.x, a20); a21 = fmaf(x2, wv.y, a21);
        a22 = fmaf(x2, wv.z, a22); a23 = fmaf(x2, wv.w, a23);
        a30 = fmaf(x3, wv.x, a30); a31 = fmaf(x3, wv.y, a31);
        a32 = fmaf(x3, wv.z, a32); a33 = fmaf(x3, wv.w, a33);
    }
    float4 rows[4] = {make_float4(a00,a01,a02,a03), make_float4(a10,a11,a12,a13),
                      make_float4(a20,a21,a22,a23), make_float4(a30,a31,a32,a33)};
#pragma unroll
    for (int i = 0; i < 4; ++i) {
        int node = node0 + nb + i;
        if (node >= N) break;
        float4 r = rows[i];
        *(float4*)(y0 + (size_t)node * H + cb) = r;
        *(unsigned*)(y0f8 + (size_t)node * H + cb) = pack_fp8x4(r.x, r.y, r.z, r.w);
    }
}

// ---------------------------------------------------------------------------
// Per-row edge count, 8-way privatized (blockIdx&7 -> XCD-local atomics)
// ---------------------------------------------------------------------------
__global__ void k_count(const int* __restrict__ row, int* __restrict__ cnt8) {
    int e = blockIdx.x * blockDim.x + threadIdx.x;
    if (e >= E) return;
    atomicAdd(&cnt8[(size_t)(blockIdx.x & 7) * N + row[e]], 1);
}

// ---------------------------------------------------------------------------
// Two-level exclusive scan of summed cnt8 -> row_ptr[]
// ---------------------------------------------------------------------------
__global__ __launch_bounds__(1024) void k_scan_blocks(const int* __restrict__ cnt8,
                                                      int* __restrict__ row_ptr,
                                                      int* __restrict__ bsum) {
    __shared__ int s[1024];
    int gid = blockIdx.x * 1024 + threadIdx.x;
    int v = 0;
    if (gid < N) {
#pragma unroll
        for (int c = 0; c < 8; ++c) v += cnt8[(size_t)c * N + gid];
    }
    s[threadIdx.x] = v;
    __syncthreads();
    for (int off = 1; off < 1024; off <<= 1) {
        int t = (threadIdx.x >= off) ? s[threadIdx.x - off] : 0;
        __syncthreads();
        s[threadIdx.x] += t;
        __syncthreads();
    }
    if (gid < N) row_ptr[gid] = s[threadIdx.x] - v;  // exclusive
    if (threadIdx.x == 1023) bsum[blockIdx.x] = s[1023];
}

__global__ void k_scan_sums(const int* __restrict__ bsum, int* __restrict__ boff, int nb) {
    int lane = threadIdx.x;
    int orig = (lane < nb) ? bsum[lane] : 0;
    int v = orig;
    for (int off = 1; off < 64; off <<= 1) {
        int t = __shfl_up(v, off, 64);
        if (lane >= off) v += t;
    }
    if (lane < nb) boff[lane] = v - orig;
}

__global__ __launch_bounds__(1024) void k_addoff(int* __restrict__ row_ptr,
                                                 const int* __restrict__ boff) {
    int gid = blockIdx.x * 1024 + threadIdx.x;
    if (gid < N) row_ptr[gid] += boff[blockIdx.x];
    if (gid == 0) row_ptr[N] = E;
}

// ---------------------------------------------------------------------------
// Turn cnt8 copies into per-copy scatter base offsets
// ---------------------------------------------------------------------------
__global__ void k_mkoff(const int* __restrict__ row_ptr, int* __restrict__ cnt8) {
    int i = blockIdx.x * blockDim.x + threadIdx.x;
    if (i >= N) return;
    int off = row_ptr[i];
#pragma unroll
    for (int c = 0; c < 8; ++c) {
        int t = cnt8[(size_t)c * N + i];
        cnt8[(size_t)c * N + i] = off;
        off += t;
    }
}

// ---------------------------------------------------------------------------
// Scatter edges into CSR; atomics only within the XCD-private copy.
// ---------------------------------------------------------------------------
__global__ void k_scatter(const int* __restrict__ row, const int* __restrict__ col,
                          const float* __restrict__ w,
                          int* __restrict__ off8, int2* __restrict__ ep) {
    int e = blockIdx.x * blockDim.x + threadIdx.x;
    if (e >= E) return;
    int r = row[e];
    int p = atomicAdd(&off8[(size_t)(blockIdx.x & 7) * N + r], 1);
    ep[p] = make_int2(col[e], __float_as_int(w[e]));
}

// ---------------------------------------------------------------------------
// Weighted degree from CSR rows + dinv/dinv2
// ---------------------------------------------------------------------------
__global__ void k_deg_dinv(const int2* __restrict__ ep, const int* __restrict__ row_ptr,
                           float* __restrict__ dinv, float* __restrict__ dinv2) {
    int i = blockIdx.x * blockDim.x + threadIdx.x;
    if (i >= N) return;
    float d = 1.0f;   // self-loop weight
    int e0 = row_ptr[i], e1 = row_ptr[i + 1];
    for (int j = e0; j < e1; ++j) d += __int_as_float(ep[j].y);
    float di = rsqrtf(d);
    dinv[i]  = di;
    dinv2[i] = di * di;
}

// ---------------------------------------------------------------------------
// Normalize edge weights in place: w <- dinv[r]*w*dinv[c]
// ---------------------------------------------------------------------------
__global__ __launch_bounds__(256) void k_norm(int2* __restrict__ ep,
                                              const int* __restrict__ row_ptr,
                                              const float* __restrict__ dinv) {
    int node = blockIdx.x * 32 + (threadIdx.x >> 3);
    if (node >= N) return;
    int l = threadIdx.x & 7;
    float dr = dinv[node];
    int e0 = row_ptr[node], e1 = row_ptr[node + 1];
    for (int j = e0 + l; j < e1; j += 8) {
        int2 v = ep[j];
        ep[j] = make_int2(v.x, __float_as_int(__int_as_float(v.y) * dr * dinv[v.x]));
    }
}

// ---------------------------------------------------------------------------
// One propagation hop, fp8 h storage (64 B row). 8 nodes per wave:
// lane = (node-sub 0..7) x (feature-octet 0..7), uint2 (8 fp8) per lane.
// 32 nodes/block -> 1563 blocks, 6250 waves. acc fp16. 2x edge unroll.
// FINAL fuses the MLP epilogue (hs stride 68 to avoid bank conflicts).
// ---------------------------------------------------------------------------
constexpr int HSP = 68;   // hs row stride in floats (nib*68: bank stride 4)
template <bool WRITE_H, bool ACC_INIT, bool FINAL>
__global__ __launch_bounds__(256) void k_prop(const uint2* __restrict__ hin,   // N x 8 (fp8x8)
                                              uint2* __restrict__ hout,
                                              __half* __restrict__ acch,       // N x H fp16
                                              const float* __restrict__ dinv2,
                                              const int* __restrict__ row_ptr,
                                              const int2* __restrict__ ep,
                                              const float4* __restrict__ y04,
                                              const float* __restrict__ b1,
                                              const float* __restrict__ W2,
                                              const float* __restrict__ b2,
                                              float* __restrict__ out) {
    extern __shared__ float smem[];          // FINAL only: w2s | hs | b2s | b1s
    float* w2s = smem;                       // H*C
    float* hs  = smem + H * C;               // 32*HSP
    float* b2s = hs + 32 * HSP;              // C
    float* b1s = b2s + C;                    // H
    int t = threadIdx.x;
    if (FINAL) {
        for (int i = t; i < H * C; i += 256) w2s[i] = W2[i];
        if (t < C) b2s[t] = b2[t];
        if (t < H) b1s[t] = b1[t];
        __syncthreads();
    }
    int lane = t & 63;
    int nib  = (t >> 6) * 8 + (lane >> 3);   // node-in-block 0..31
    int l    = lane & 7;                     // feature octet (features 8l..8l+7)
    int node = blockIdx.x * 32 + nib;
    bool nv  = node < N;
    int nodec = nv ? node : N - 1;
    int start = row_ptr[nodec];
    int deg   = nv ? (row_ptr[nodec + 1] - start) : 0;
    int md = deg;                            // max degree across the wave's 8 nodes
    md = max(md, __shfl_xor(md, 8, 64));
    md = max(md, __shfl_xor(md, 16, 64));
    md = max(md, __shfl_xor(md, 32, 64));
    float s[8];
#pragma unroll
    for (int i = 0; i < 8; ++i) s[i] = 0.0f;
    auto accum = [&](uint2 v, float w) {
        v2f a0 = __builtin_amdgcn_cvt_pk_f32_fp8(v.x, false);
        v2f b0 = __builtin_amdgcn_cvt_pk_f32_fp8(v.x, true);
        v2f a1 = __builtin_amdgcn_cvt_pk_f32_fp8(v.y, false);
        v2f b1v = __builtin_amdgcn_cvt_pk_f32_fp8(v.y, true);
        s[0] = fmaf(w, a0.x, s[0]); s[1] = fmaf(w, a0.y, s[1]);
        s[2] = fmaf(w, b0.x, s[2]); s[3] = fmaf(w, b0.y, s[3]);
        s[4] = fmaf(w, a1.x, s[4]); s[5] = fmaf(w, a1.y, s[5]);
        s[6] = fmaf(w, b1v.x, s[6]); s[7] = fmaf(w, b1v.y, s[7]);
    };
    for (int j = 0; j < md; j += 2) {
        bool a0 = j < deg, a1 = j + 1 < deg;
        int2 e0 = ep[a0 ? start + j     : 0];
        int2 e1 = ep[a1 ? start + j + 1 : 0];
        uint2 v0 = hin[(size_t)e0.x * 8 + l];
        uint2 v1 = hin[(size_t)e1.x * 8 + l];
        float w0 = a0 ? __int_as_float(e0.y) : 0.0f;
        float w1 = a1 ? __int_as_float(e1.y) : 0.0f;
        accum(v0, w0);
        accum(v1, w1);
    }
    if (nv) {
        size_t base = (size_t)node * 8 + l;
        accum(hin[base], dinv2[node]);       // self-loop term
        if (WRITE_H) {
            uint2 o;
            o.x = pack_fp8x4(s[0], s[1], s[2], s[3]);
            o.y = pack_fp8x4(s[4], s[5], s[6], s[7]);
            hout[base] = o;
        }
        uint4* ap = (uint4*)(acch + (size_t)node * H + l * 8);   // 8 halves = 16 B
        if (FINAL) {
            uint4 old = *ap;
            const unsigned* u = (const unsigned*)&old;
#pragma unroll
            for (int d = 0; d < 4; ++d) {
                float2 f = __half22float2(*(__half2*)&u[d]);
                s[2*d+0] += f.x; s[2*d+1] += f.y;
            }
            float4 ya = y04[(size_t)node * (H / 4) + 2 * l];
            float4 yb = y04[(size_t)node * (H / 4) + 2 * l + 1];
            const float* bp = b1s + l * 8;
            float* hp = hs + nib * HSP + l * 8;
            hp[0] = fmaxf(fmaf(CK, s[0], fmaf(AL, ya.x, bp[0])), 0.f);
            hp[1] = fmaxf(fmaf(CK, s[1], fmaf(AL, ya.y, bp[1])), 0.f);
            hp[2] = fmaxf(fmaf(CK, s[2], fmaf(AL, ya.z, bp[2])), 0.f);
            hp[3] = fmaxf(fmaf(CK, s[3], fmaf(AL, ya.w, bp[3])), 0.f);
            hp[4] = fmaxf(fmaf(CK, s[4], fmaf(AL, yb.x, bp[4])), 0.f);
            hp[5] = fmaxf(fmaf(CK, s[5], fmaf(AL, yb.y, bp[5])), 0.f);
            hp[6] = fmaxf(fmaf(CK, s[6], fmaf(AL, yb.z, bp[6])), 0.f);
            hp[7] = fmaxf(fmaf(CK, s[7], fmaf(AL, yb.w, bp[7])), 0.f);
        } else {
            if (!ACC_INIT) {
                uint4 old = *ap;
                const unsigned* u = (const unsigned*)&old;
#pragma unroll
                for (int d = 0; d < 4; ++d) {
                    float2 f = __half22float2(*(__half2*)&u[d]);
                    s[2*d+0] += f.x; s[2*d+1] += f.y;
                }
            }
            uint4 nvp;
            unsigned* u = (unsigned*)&nvp;
#pragma unroll
            for (int d = 0; d < 4; ++d) {
                __half2 h = __floats2half2_rn(s[2*d+0], s[2*d+1]);
                u[d] = *(unsigned*)&h;
            }
            *ap = nvp;
        }
    }
    if (FINAL) {
        __syncthreads();
        int node0 = blockIdx.x * 32;
        for (int o = t; o < 32 * C; o += 256) {
            int nl = o / C, c = o % C;
            int n2 = node0 + nl;
            if (n2 >= N) continue;
            float v = b2s[c];
            const float* hr = &hs[nl * HSP];
#pragma unroll
            for (int k = 0; k < H; ++k) v = fmaf(hr[k], w2s[k * C + c], v);
            out[n2 * C + c] = v;
        }
    }
}

// ---------------------------------------------------------------------------
extern "C" void kernel_launch(void* const* d_in, const int* in_sizes, int n_in,
                              void* d_out, int out_size, void* d_ws, size_t ws_size,
                              hipStream_t stream) {
    const float* x  = (const float*)d_in[0];
    const int*   ei = (const int*)d_in[1];
    const float* ew = (const float*)d_in[2];
    const float* W1 = (const float*)d_in[3];
    const float* b1 = (const float*)d_in[4];
    const float* W2 = (const float*)d_in[5];
    const float* b2 = (const float*)d_in[6];
    float* out = (float*)d_out;

    const int* row = ei;        // edge_index[0]
    const int* col = ei + E;    // edge_index[1]

    char* ws = (char*)d_ws;
    size_t off = 0;
    auto alloc = [&](size_t bytes) -> char* {
        char* p = ws + off;
        off = (off + bytes + 1023) & ~(size_t)1023;
        return p;
    };
    float*         y0   = (float*)alloc((size_t)N * H * 4);
    unsigned char* y0f8 = (unsigned char*)alloc((size_t)N * H);
    unsigned char* ha   = (unsigned char*)alloc((size_t)N * H);
    unsigned char* hb   = (unsigned char*)alloc((size_t)N * H);
    __half*        acch = (__half*)alloc((size_t)N * H * 2);
    int*   cnt8   = (int*)  alloc((size_t)8 * N * 4);  // zeroed
    float* dinv   = (float*)alloc((size_t)N * 4);
    float* dinv2  = (float*)alloc((size_t)N * 4);
    int*   row_ptr= (int*)  alloc((size_t)(N + 1) * 4);
    int*   bsum   = (int*)  alloc(64 * 4);
    int*   boff   = (int*)  alloc(64 * 4);
    int2*  ep     = (int2*) alloc((size_t)E * 8);

    hipMemsetAsync(cnt8, 0, (size_t)8 * N * 4, stream);

    // 1) y0 = x @ W1 (fp32 + fp8)
    k_gemm1<<<(N + G1N - 1) / G1N, 256, 0, stream>>>(x, W1, y0, y0f8);

    // 2) per-row edge counts (XCD-privatized)
    k_count<<<(E + 255) / 256, 256, 0, stream>>>(row, cnt8);

    // 3) scan counts -> row_ptr; build per-copy scatter offsets
    constexpr int NB = (N + 1023) / 1024;  // 49
    k_scan_blocks<<<NB, 1024, 0, stream>>>(cnt8, row_ptr, bsum);
    k_scan_sums<<<1, 64, 0, stream>>>(bsum, boff, NB);
    k_addoff<<<NB, 1024, 0, stream>>>(row_ptr, boff);
    k_mkoff<<<(N + 255) / 256, 256, 0, stream>>>(row_ptr, cnt8);

    // 4) CSR scatter (XCD-private atomics), weighted degree + dinv, normalize
    k_scatter<<<(E + 255) / 256, 256, 0, stream>>>(row, col, ew, cnt8, ep);
    k_deg_dinv<<<(N + 255) / 256, 256, 0, stream>>>(ep, row_ptr, dinv, dinv2);
    k_norm<<<(N + 31) / 32, 256, 0, stream>>>(ep, row_ptr, dinv);

    // 5) K hops; hop 0 inits acc, hop K-1 fuses the MLP epilogue
    const uint2* hin = (const uint2*)y0f8;
    uint2* bufs[2] = {(uint2*)ha, (uint2*)hb};
    int grid = (N + 31) / 32;   // 1563 blocks, 32 nodes/block
    size_t smemF = (size_t)(H * C + 32 * HSP + C + H) * 4;
    for (int hop = 0; hop < K; ++hop) {
        uint2* hout = bufs[hop & 1];
        if (hop == 0)
            k_prop<true, true, false><<<grid, 256, 0, stream>>>(hin, hout, acch, dinv2,
                row_ptr, ep, (const float4*)y0, b1, W2, b2, out);
        else if (hop == K - 1)
            k_prop<false, false, true><<<grid, 256, smemF, stream>>>(hin, hout, acch, dinv2,
                row_ptr, ep, (const float4*)y0, b1, W2, b2, out);
        else
            k_prop<true, false, false><<<grid, 256, 0, stream>>>(hin, hout, acch, dinv2,
                row_ptr, ep, (const float4*)y0, b1, W2, b2, out);
        hin = hout;
    }
}

// Round 11
// 342.906 us; speedup vs baseline: 1.2656x; 1.0013x over previous
//
#include <hip/hip_runtime.h>
#include <hip/hip_fp16.h>
#include <hip/hip_cooperative_groups.h>
#include <math.h>

namespace cg = cooperative_groups;

// Problem constants (fixed by the reference)
constexpr int   N   = 50000;
constexpr int   E   = 600000;
constexpr int   FIN = 128;
constexpr int   H   = 64;
constexpr int   C   = 40;
constexpr int   K   = 10;
constexpr float CK  = (1.0f - 0.1f) / 10.0f;  // (1-alpha)/K
constexpr float AL  = 0.1f;                   // alpha

typedef float v2f __attribute__((ext_vector_type(2)));

// pack 4 fp32 -> 4 fp8 e4m3 (HW RNE, OCP on gfx950)
__device__ __forceinline__ unsigned pack_fp8x4(float f0, float f1, float f2, float f3) {
    unsigned r = __builtin_amdgcn_cvt_pk_fp8_f32(f0, f1, 0u, false);
    r = __builtin_amdgcn_cvt_pk_fp8_f32(f2, f3, r, true);
    return r;
}

// ---------------------------------------------------------------------------
// y0 = x @ W1   (N x 128) @ (128 x 64)
// ---------------------------------------------------------------------------
constexpr int G1N  = 64;
constexpr int XPAD = 132;
__global__ __launch_bounds__(256, 2) void k_gemm1(const float* __restrict__ x,
                                                  const float* __restrict__ W1,
                                                  float* __restrict__ y0,
                                                  unsigned char* __restrict__ y0f8) {
    __shared__ float ws[FIN * H];
    __shared__ float xs[G1N * XPAD];
    const float4* W14 = (const float4*)W1;
    const float4* x4  = (const float4*)x;
    int t = threadIdx.x;
    int node0 = blockIdx.x * G1N;
    for (int i = t; i < FIN * H / 4; i += 256) ((float4*)ws)[i] = W14[i];
    for (int p = 0; p < 8; ++p) {
        int idx = p * 256 + t;
        int n   = idx >> 5;
        int kk  = idx & 31;
        int node = node0 + n;
        float4 v = (node < N) ? x4[(size_t)node * (FIN / 4) + kk]
                              : make_float4(0.f, 0.f, 0.f, 0.f);
        *(float4*)(xs + n * XPAD + kk * 4) = v;
    }
    __syncthreads();
    int nb = (t >> 4) * 4;
    int cb = (t & 15) * 4;
    float a00=0,a01=0,a02=0,a03=0, a10=0,a11=0,a12=0,a13=0;
    float a20=0,a21=0,a22=0,a23=0, a30=0,a31=0,a32=0,a33=0;
#pragma unroll 8
    for (int k = 0; k < FIN; ++k) {
        float4 wv = *(const float4*)(ws + k * H + cb);
        float x0 = xs[(nb + 0) * XPAD + k];
        float x1 = xs[(nb + 1) * XPAD + k];
        float x2 = xs[(nb + 2) * XPAD + k];
        float x3 = xs[(nb + 3) * XPAD + k];
        a00 = fmaf(x0, wv.x, a00); a01 = fmaf(x0, wv.y, a01);
        a02 = fmaf(x0, wv.z, a02); a03 = fmaf(x0, wv.w, a03);
        a10 = fmaf(x1, wv.x, a10); a11 = fmaf(x1, wv.y, a11);
        a12 = fmaf(x1, wv.z, a12); a13 = fmaf(x1, wv.w, a13);
        a20 = fmaf(x2, wv.x, a20); a21 = fmaf(x2, wv.y, a21);
        a22 = fmaf(x2, wv.z, a22); a23 = fmaf(x2, wv.w, a23);
        a30 = fmaf(x3, wv.x, a30); a31 = fmaf(x3, wv.y, a31);
        a32 = fmaf(x3, wv.z, a32); a33 = fmaf(x3, wv.w, a33);
    }
    float4 rows[4] = {make_float4(a00,a01,a02,a03), make_float4(a10,a11,a12,a13),
                      make_float4(a20,a21,a22,a23), make_float4(a30,a31,a32,a33)};
#pragma unroll
    for (int i = 0; i < 4; ++i) {
        int node = node0 + nb + i;
        if (node >= N) break;
        float4 r = rows[i];
        *(float4*)(y0 + (size_t)node * H + cb) = r;
        *(unsigned*)(y0f8 + (size_t)node * H + cb) = pack_fp8x4(r.x, r.y, r.z, r.w);
    }
}

// ---------------------------------------------------------------------------
// Per-row edge count, 8-way privatized
// ---------------------------------------------------------------------------
__global__ void k_count(const int* __restrict__ row, int* __restrict__ cnt8) {
    int e = blockIdx.x * blockDim.x + threadIdx.x;
    if (e >= E) return;
    atomicAdd(&cnt8[(size_t)(blockIdx.x & 7) * N + row[e]], 1);
}

// ---------------------------------------------------------------------------
// Two-level exclusive scan of summed cnt8 -> row_ptr[]
// ---------------------------------------------------------------------------
__global__ __launch_bounds__(1024) void k_scan_blocks(const int* __restrict__ cnt8,
                                                      int* __restrict__ row_ptr,
                                                      int* __restrict__ bsum) {
    __shared__ int s[1024];
    int gid = blockIdx.x * 1024 + threadIdx.x;
    int v = 0;
    if (gid < N) {
#pragma unroll
        for (int c = 0; c < 8; ++c) v += cnt8[(size_t)c * N + gid];
    }
    s[threadIdx.x] = v;
    __syncthreads();
    for (int off = 1; off < 1024; off <<= 1) {
        int t = (threadIdx.x >= off) ? s[threadIdx.x - off] : 0;
        __syncthreads();
        s[threadIdx.x] += t;
        __syncthreads();
    }
    if (gid < N) row_ptr[gid] = s[threadIdx.x] - v;  // exclusive
    if (threadIdx.x == 1023) bsum[blockIdx.x] = s[1023];
}

__global__ void k_scan_sums(const int* __restrict__ bsum, int* __restrict__ boff, int nb) {
    int lane = threadIdx.x;
    int orig = (lane < nb) ? bsum[lane] : 0;
    int v = orig;
    for (int off = 1; off < 64; off <<= 1) {
        int t = __shfl_up(v, off, 64);
        if (lane >= off) v += t;
    }
    if (lane < nb) boff[lane] = v - orig;
}

__global__ __launch_bounds__(1024) void k_addoff(int* __restrict__ row_ptr,
                                                 const int* __restrict__ boff) {
    int gid = blockIdx.x * 1024 + threadIdx.x;
    if (gid < N) row_ptr[gid] += boff[blockIdx.x];
    if (gid == 0) row_ptr[N] = E;
}

// ---------------------------------------------------------------------------
// Turn cnt8 copies into per-copy scatter base offsets
// ---------------------------------------------------------------------------
__global__ void k_mkoff(const int* __restrict__ row_ptr, int* __restrict__ cnt8) {
    int i = blockIdx.x * blockDim.x + threadIdx.x;
    if (i >= N) return;
    int off = row_ptr[i];
#pragma unroll
    for (int c = 0; c < 8; ++c) {
        int t = cnt8[(size_t)c * N + i];
        cnt8[(size_t)c * N + i] = off;
        off += t;
    }
}

// ---------------------------------------------------------------------------
// Scatter edges into CSR; atomics within XCD-private copy
// ---------------------------------------------------------------------------
__global__ void k_scatter(const int* __restrict__ row, const int* __restrict__ col,
                          const float* __restrict__ w,
                          int* __restrict__ off8, int2* __restrict__ ep) {
    int e = blockIdx.x * blockDim.x + threadIdx.x;
    if (e >= E) return;
    int r = row[e];
    int p = atomicAdd(&off8[(size_t)(blockIdx.x & 7) * N + r], 1);
    ep[p] = make_int2(col[e], __float_as_int(w[e]));
}

// ---------------------------------------------------------------------------
// Weighted degree + dinv/dinv2
// ---------------------------------------------------------------------------
__global__ void k_deg_dinv(const int2* __restrict__ ep, const int* __restrict__ row_ptr,
                           float* __restrict__ dinv, float* __restrict__ dinv2) {
    int i = blockIdx.x * blockDim.x + threadIdx.x;
    if (i >= N) return;
    float d = 1.0f;
    int e0 = row_ptr[i], e1 = row_ptr[i + 1];
    for (int j = e0; j < e1; ++j) d += __int_as_float(ep[j].y);
    float di = rsqrtf(d);
    dinv[i]  = di;
    dinv2[i] = di * di;
}

// ---------------------------------------------------------------------------
// Normalize edge weights in place
// ---------------------------------------------------------------------------
__global__ __launch_bounds__(256) void k_norm(int2* __restrict__ ep,
                                              const int* __restrict__ row_ptr,
                                              const float* __restrict__ dinv) {
    int node = blockIdx.x * 32 + (threadIdx.x >> 3);
    if (node >= N) return;
    int l = threadIdx.x & 7;
    float dr = dinv[node];
    int e0 = row_ptr[node], e1 = row_ptr[node + 1];
    for (int j = e0 + l; j < e1; j += 8) {
        int2 v = ep[j];
        ep[j] = make_int2(v.x, __float_as_int(__int_as_float(v.y) * dr * dinv[v.x]));
    }
}

// ---------------------------------------------------------------------------
// Shared chunk worker: gather + self-term; acc += s; optional h write.
// ---------------------------------------------------------------------------
__device__ __forceinline__ void prop_chunk(const uint2* __restrict__ hin,
                                           uint2* __restrict__ hout,
                                           const int2* __restrict__ ep,
                                           int start, int deg, int md,
                                           float d2, int nc, bool nv, int l,
                                           bool writeH, float* acc, float* sout) {
    float s[8];
#pragma unroll
    for (int i = 0; i < 8; ++i) s[i] = 0.f;
    for (int j = 0; j < md; j += 2) {
        bool a0 = j < deg, a1 = j + 1 < deg;
        int2 e0 = ep[a0 ? start + j     : 0];
        int2 e1 = ep[a1 ? start + j + 1 : 0];
        uint2 v0 = hin[(size_t)e0.x * 8 + l];
        uint2 v1 = hin[(size_t)e1.x * 8 + l];
        float w0 = a0 ? __int_as_float(e0.y) : 0.0f;
        float w1 = a1 ? __int_as_float(e1.y) : 0.0f;
        {
            v2f p0 = __builtin_amdgcn_cvt_pk_f32_fp8(v0.x, false);
            v2f p1 = __builtin_amdgcn_cvt_pk_f32_fp8(v0.x, true);
            v2f p2 = __builtin_amdgcn_cvt_pk_f32_fp8(v0.y, false);
            v2f p3 = __builtin_amdgcn_cvt_pk_f32_fp8(v0.y, true);
            s[0] = fmaf(w0, p0.x, s[0]); s[1] = fmaf(w0, p0.y, s[1]);
            s[2] = fmaf(w0, p1.x, s[2]); s[3] = fmaf(w0, p1.y, s[3]);
            s[4] = fmaf(w0, p2.x, s[4]); s[5] = fmaf(w0, p2.y, s[5]);
            s[6] = fmaf(w0, p3.x, s[6]); s[7] = fmaf(w0, p3.y, s[7]);
        }
        {
            v2f p0 = __builtin_amdgcn_cvt_pk_f32_fp8(v1.x, false);
            v2f p1 = __builtin_amdgcn_cvt_pk_f32_fp8(v1.x, true);
            v2f p2 = __builtin_amdgcn_cvt_pk_f32_fp8(v1.y, false);
            v2f p3 = __builtin_amdgcn_cvt_pk_f32_fp8(v1.y, true);
            s[0] = fmaf(w1, p0.x, s[0]); s[1] = fmaf(w1, p0.y, s[1]);
            s[2] = fmaf(w1, p1.x, s[2]); s[3] = fmaf(w1, p1.y, s[3]);
            s[4] = fmaf(w1, p2.x, s[4]); s[5] = fmaf(w1, p2.y, s[5]);
            s[6] = fmaf(w1, p3.x, s[6]); s[7] = fmaf(w1, p3.y, s[7]);
        }
    }
    if (nv) {
        uint2 hv = hin[(size_t)nc * 8 + l];
        v2f p0 = __builtin_amdgcn_cvt_pk_f32_fp8(hv.x, false);
        v2f p1 = __builtin_amdgcn_cvt_pk_f32_fp8(hv.x, true);
        v2f p2 = __builtin_amdgcn_cvt_pk_f32_fp8(hv.y, false);
        v2f p3 = __builtin_amdgcn_cvt_pk_f32_fp8(hv.y, true);
        s[0] = fmaf(d2, p0.x, s[0]); s[1] = fmaf(d2, p0.y, s[1]);
        s[2] = fmaf(d2, p1.x, s[2]); s[3] = fmaf(d2, p1.y, s[3]);
        s[4] = fmaf(d2, p2.x, s[4]); s[5] = fmaf(d2, p2.y, s[5]);
        s[6] = fmaf(d2, p3.x, s[6]); s[7] = fmaf(d2, p3.y, s[7]);
        if (acc) {
#pragma unroll
            for (int i = 0; i < 8; ++i) acc[i] += s[i];
        }
        if (writeH) {
            uint2 o;
            o.x = pack_fp8x4(s[0], s[1], s[2], s[3]);
            o.y = pack_fp8x4(s[4], s[5], s[6], s[7]);
            hout[(size_t)nc * 8 + l] = o;
        }
    }
    if (sout) {
#pragma unroll
        for (int i = 0; i < 8; ++i) sout[i] = s[i];
    }
}

// ---------------------------------------------------------------------------
// COOPERATIVE: all K hops + MLP epilogue in ONE kernel.
// 782 blocks x 64 nodes (2 chunks of 32), 8 nodes/wave, acc in VGPRs.
// __launch_bounds__(256,4): <=128 VGPR -> 4 blocks/CU -> 1024 >= 782.
// ---------------------------------------------------------------------------
constexpr int NBLK = 782;
constexpr int NPB  = 64;
constexpr int HSP  = 68;

__global__ __launch_bounds__(256, 4) void k_hops(const uint2* __restrict__ y0f8,
                                                 uint2* __restrict__ ha,
                                                 uint2* __restrict__ hb,
                                                 const float* __restrict__ dinv2,
                                                 const int* __restrict__ row_ptr,
                                                 const int2* __restrict__ ep,
                                                 const float4* __restrict__ y04,
                                                 const float* __restrict__ b1,
                                                 const float* __restrict__ W2,
                                                 const float* __restrict__ b2,
                                                 float* __restrict__ out) {
    cg::grid_group grid = cg::this_grid();
    __shared__ float w2s[H * C];        // 10 KB
    __shared__ float hs[NPB * HSP];     // 17 KB
    __shared__ float b2s[C];
    __shared__ float b1s[H];
    __shared__ int   s_deg[NPB];
    __shared__ int   s_sorted[NPB];
    int t = threadIdx.x;
    int node0 = blockIdx.x * NPB;

    for (int i = t; i < H * C; i += 256) w2s[i] = W2[i];
    if (t < C) b2s[t] = b2[t];
    if (t < H) b1s[t] = b1[t];

    // block-local degree sort (rank-based), once for all hops
    if (t < NPB) {
        int n = node0 + t;
        s_deg[t] = (n < N) ? row_ptr[n + 1] - row_ptr[n] : -1;
    }
    __syncthreads();
    if (t < NPB) {
        int d = s_deg[t];
        int rank = 0;
        for (int j = 0; j < NPB; ++j) {
            int dj = s_deg[j];
            rank += (dj < d) || (dj == d && j < t);
        }
        s_sorted[rank] = t;
    }
    __syncthreads();

    int lane = t & 63;
    int wv   = t >> 6;
    int sub  = lane >> 3;
    int l    = lane & 7;
    int nibA = s_sorted[wv * 8 + sub];
    int nibB = s_sorted[32 + wv * 8 + sub];
    int nodeA = node0 + nibA;
    int nodeB = node0 + nibB;
    bool nvA = nodeA < N, nvB = nodeB < N;
    int ncA = nvA ? nodeA : 0, ncB = nvB ? nodeB : 0;
    int startA = row_ptr[ncA], degA = nvA ? (row_ptr[ncA + 1] - startA) : 0;
    int startB = row_ptr[ncB], degB = nvB ? (row_ptr[ncB + 1] - startB) : 0;
    float d2A = nvA ? dinv2[ncA] : 0.f;
    float d2B = nvB ? dinv2[ncB] : 0.f;
    int mdA = degA, mdB = degB;
#pragma unroll
    for (int off = 8; off <= 32; off <<= 1) {
        mdA = max(mdA, __shfl_xor(mdA, off, 64));
        mdB = max(mdB, __shfl_xor(mdB, off, 64));
    }

    float accA[8], accB[8];
#pragma unroll
    for (int i = 0; i < 8; ++i) { accA[i] = 0.f; accB[i] = 0.f; }

    const uint2* hin = y0f8;
    uint2* hbuf[2] = {ha, hb};

    for (int hop = 0; hop < K; ++hop) {
        uint2* hout = hbuf[hop & 1];
        bool writeH = hop < K - 1;
        prop_chunk(hin, hout, ep, startA, degA, mdA, d2A, ncA, nvA, l, writeH, accA, nullptr);
        prop_chunk(hin, hout, ep, startB, degB, mdB, d2B, ncB, nvB, l, writeH, accB, nullptr);
        if (hop < K - 1) {
            grid.sync();
            hin = hout;
        }
    }

    // fused MLP epilogue
    if (nvA) {
        float4 ya = y04[(size_t)ncA * (H / 4) + 2 * l];
        float4 yb = y04[(size_t)ncA * (H / 4) + 2 * l + 1];
        const float* bp = b1s + l * 8;
        float* hp = hs + nibA * HSP + l * 8;
        hp[0] = fmaxf(fmaf(CK, accA[0], fmaf(AL, ya.x, bp[0])), 0.f);
        hp[1] = fmaxf(fmaf(CK, accA[1], fmaf(AL, ya.y, bp[1])), 0.f);
        hp[2] = fmaxf(fmaf(CK, accA[2], fmaf(AL, ya.z, bp[2])), 0.f);
        hp[3] = fmaxf(fmaf(CK, accA[3], fmaf(AL, ya.w, bp[3])), 0.f);
        hp[4] = fmaxf(fmaf(CK, accA[4], fmaf(AL, yb.x, bp[4])), 0.f);
        hp[5] = fmaxf(fmaf(CK, accA[5], fmaf(AL, yb.y, bp[5])), 0.f);
        hp[6] = fmaxf(fmaf(CK, accA[6], fmaf(AL, yb.z, bp[6])), 0.f);
        hp[7] = fmaxf(fmaf(CK, accA[7], fmaf(AL, yb.w, bp[7])), 0.f);
    }
    if (nvB) {
        float4 ya = y04[(size_t)ncB * (H / 4) + 2 * l];
        float4 yb = y04[(size_t)ncB * (H / 4) + 2 * l + 1];
        const float* bp = b1s + l * 8;
        float* hp = hs + nibB * HSP + l * 8;
        hp[0] = fmaxf(fmaf(CK, accB[0], fmaf(AL, ya.x, bp[0])), 0.f);
        hp[1] = fmaxf(fmaf(CK, accB[1], fmaf(AL, ya.y, bp[1])), 0.f);
        hp[2] = fmaxf(fmaf(CK, accB[2], fmaf(AL, ya.z, bp[2])), 0.f);
        hp[3] = fmaxf(fmaf(CK, accB[3], fmaf(AL, ya.w, bp[3])), 0.f);
        hp[4] = fmaxf(fmaf(CK, accB[4], fmaf(AL, yb.x, bp[4])), 0.f);
        hp[5] = fmaxf(fmaf(CK, accB[5], fmaf(AL, yb.y, bp[5])), 0.f);
        hp[6] = fmaxf(fmaf(CK, accB[6], fmaf(AL, yb.z, bp[6])), 0.f);
        hp[7] = fmaxf(fmaf(CK, accB[7], fmaf(AL, yb.w, bp[7])), 0.f);
    }
    __syncthreads();
    for (int o = t; o < NPB * C; o += 256) {
        int nl = o / C, c = o % C;
        int n2 = node0 + nl;
        if (n2 >= N) continue;
        float v = b2s[c];
        const float* hr = &hs[nl * HSP];
#pragma unroll
        for (int k = 0; k < H; ++k) v = fmaf(hr[k], w2s[k * C + c], v);
        out[n2 * C + c] = v;
    }
}

// ---------------------------------------------------------------------------
// FALLBACK: R9 per-hop kernel (fp16 acc in global) — used only if the
// cooperative launch can't fit (occupancy check), guaranteeing correctness.
// ---------------------------------------------------------------------------
template <bool WRITE_H, bool ACC_INIT, bool FINAL>
__global__ __launch_bounds__(256) void k_prop(const uint2* __restrict__ hin,
                                              uint2* __restrict__ hout,
                                              __half* __restrict__ acch,
                                              const float* __restrict__ dinv2,
                                              const int* __restrict__ row_ptr,
                                              const int2* __restrict__ ep,
                                              const float4* __restrict__ y04,
                                              const float* __restrict__ b1,
                                              const float* __restrict__ W2,
                                              const float* __restrict__ b2,
                                              float* __restrict__ out) {
    extern __shared__ float smem[];
    float* w2s = smem;
    float* hs  = smem + H * C;
    float* b2s = hs + 32 * HSP;
    float* b1s = b2s + C;
    int t = threadIdx.x;
    if (FINAL) {
        for (int i = t; i < H * C; i += 256) w2s[i] = W2[i];
        if (t < C) b2s[t] = b2[t];
        if (t < H) b1s[t] = b1[t];
        __syncthreads();
    }
    int lane = t & 63;
    int nib  = (t >> 6) * 8 + (lane >> 3);
    int l    = lane & 7;
    int node = blockIdx.x * 32 + nib;
    bool nv  = node < N;
    int nodec = nv ? node : N - 1;
    int start = row_ptr[nodec];
    int deg   = nv ? (row_ptr[nodec + 1] - start) : 0;
    int md = deg;
#pragma unroll
    for (int off = 8; off <= 32; off <<= 1) md = max(md, __shfl_xor(md, off, 64));
    float s[8];
    prop_chunk(hin, hout, ep, start, deg, md, nv ? dinv2[nodec] : 0.f, nodec, nv,
               l, false, nullptr, s);
    if (nv) {
        if (WRITE_H) {
            uint2 o;
            o.x = pack_fp8x4(s[0], s[1], s[2], s[3]);
            o.y = pack_fp8x4(s[4], s[5], s[6], s[7]);
            hout[(size_t)nodec * 8 + l] = o;
        }
        uint4* ap = (uint4*)(acch + (size_t)nodec * H + l * 8);
        if (FINAL) {
            uint4 old = *ap;
            const unsigned* u = (const unsigned*)&old;
#pragma unroll
            for (int d = 0; d < 4; ++d) {
                float2 f = __half22float2(*(__half2*)&u[d]);
                s[2*d+0] += f.x; s[2*d+1] += f.y;
            }
            float4 ya = y04[(size_t)nodec * (H / 4) + 2 * l];
            float4 yb = y04[(size_t)nodec * (H / 4) + 2 * l + 1];
            const float* bp = b1s + l * 8;
            float* hp = hs + nib * HSP + l * 8;
            hp[0] = fmaxf(fmaf(CK, s[0], fmaf(AL, ya.x, bp[0])), 0.f);
            hp[1] = fmaxf(fmaf(CK, s[1], fmaf(AL, ya.y, bp[1])), 0.f);
            hp[2] = fmaxf(fmaf(CK, s[2], fmaf(AL, ya.z, bp[2])), 0.f);
            hp[3] = fmaxf(fmaf(CK, s[3], fmaf(AL, ya.w, bp[3])), 0.f);
            hp[4] = fmaxf(fmaf(CK, s[4], fmaf(AL, yb.x, bp[4])), 0.f);
            hp[5] = fmaxf(fmaf(CK, s[5], fmaf(AL, yb.y, bp[5])), 0.f);
            hp[6] = fmaxf(fmaf(CK, s[6], fmaf(AL, yb.z, bp[6])), 0.f);
            hp[7] = fmaxf(fmaf(CK, s[7], fmaf(AL, yb.w, bp[7])), 0.f);
        } else {
            if (!ACC_INIT) {
                uint4 old = *ap;
                const unsigned* u = (const unsigned*)&old;
#pragma unroll
                for (int d = 0; d < 4; ++d) {
                    float2 f = __half22float2(*(__half2*)&u[d]);
                    s[2*d+0] += f.x; s[2*d+1] += f.y;
                }
            }
            uint4 nvp;
            unsigned* u = (unsigned*)&nvp;
#pragma unroll
            for (int d = 0; d < 4; ++d) {
                __half2 h = __floats2half2_rn(s[2*d+0], s[2*d+1]);
                u[d] = *(unsigned*)&h;
            }
            *ap = nvp;
        }
    }
    if (FINAL) {
        __syncthreads();
        int node0 = blockIdx.x * 32;
        for (int o = t; o < 32 * C; o += 256) {
            int nl = o / C, c = o % C;
            int n2 = node0 + nl;
            if (n2 >= N) continue;
            float v = b2s[c];
            const float* hr = &hs[nl * HSP];
#pragma unroll
            for (int k = 0; k < H; ++k) v = fmaf(hr[k], w2s[k * C + c], v);
            out[n2 * C + c] = v;
        }
    }
}

// ---------------------------------------------------------------------------
extern "C" void kernel_launch(void* const* d_in, const int* in_sizes, int n_in,
                              void* d_out, int out_size, void* d_ws, size_t ws_size,
                              hipStream_t stream) {
    const float* x  = (const float*)d_in[0];
    const int*   ei = (const int*)d_in[1];
    const float* ew = (const float*)d_in[2];
    const float* W1 = (const float*)d_in[3];
    const float* b1 = (const float*)d_in[4];
    const float* W2 = (const float*)d_in[5];
    const float* b2 = (const float*)d_in[6];
    float* out = (float*)d_out;

    const int* row = ei;
    const int* col = ei + E;

    char* ws = (char*)d_ws;
    size_t off = 0;
    auto alloc = [&](size_t bytes) -> char* {
        char* p = ws + off;
        off = (off + bytes + 1023) & ~(size_t)1023;
        return p;
    };
    float*         y0   = (float*)alloc((size_t)N * H * 4);
    unsigned char* y0f8 = (unsigned char*)alloc((size_t)N * H);
    unsigned char* ha   = (unsigned char*)alloc((size_t)N * H);
    unsigned char* hb   = (unsigned char*)alloc((size_t)N * H);
    __half*        acch = (__half*)alloc((size_t)N * H * 2);
    int*   cnt8   = (int*)  alloc((size_t)8 * N * 4);  // zeroed
    float* dinv   = (float*)alloc((size_t)N * 4);
    float* dinv2  = (float*)alloc((size_t)N * 4);
    int*   row_ptr= (int*)  alloc((size_t)(N + 1) * 4);
    int*   bsum   = (int*)  alloc(64 * 4);
    int*   boff   = (int*)  alloc(64 * 4);
    int2*  ep     = (int2*) alloc((size_t)E * 8);

    hipMemsetAsync(cnt8, 0, (size_t)8 * N * 4, stream);

    // 1) y0 = x @ W1 (fp32 + fp8)
    k_gemm1<<<(N + G1N - 1) / G1N, 256, 0, stream>>>(x, W1, y0, y0f8);

    // 2) per-row edge counts
    k_count<<<(E + 255) / 256, 256, 0, stream>>>(row, cnt8);

    // 3) scan -> row_ptr; per-copy scatter offsets
    constexpr int NB = (N + 1023) / 1024;  // 49
    k_scan_blocks<<<NB, 1024, 0, stream>>>(cnt8, row_ptr, bsum);
    k_scan_sums<<<1, 64, 0, stream>>>(bsum, boff, NB);
    k_addoff<<<NB, 1024, 0, stream>>>(row_ptr, boff);
    k_mkoff<<<(N + 255) / 256, 256, 0, stream>>>(row_ptr, cnt8);

    // 4) scatter, degree, normalize
    k_scatter<<<(E + 255) / 256, 256, 0, stream>>>(row, col, ew, cnt8, ep);
    k_deg_dinv<<<(N + 255) / 256, 256, 0, stream>>>(ep, row_ptr, dinv, dinv2);
    k_norm<<<(N + 31) / 32, 256, 0, stream>>>(ep, row_ptr, dinv);

    // 5) hops: cooperative single-kernel if it fits, else R9 fallback loop
    const uint2* y0f8c = (const uint2*)y0f8;
    uint2* hac = (uint2*)ha;
    uint2* hbc = (uint2*)hb;
    const float4* y04 = (const float4*)y0;

    int maxBlkPerCU = 0;
    hipError_t oe = hipOccupancyMaxActiveBlocksPerMultiprocessor(&maxBlkPerCU,
                                                                 k_hops, 256, 0);
    bool coop_ok = (oe == hipSuccess) && ((long)maxBlkPerCU * 256 >= NBLK);

    if (coop_ok) {
        void* args[] = {(void*)&y0f8c, (void*)&hac, (void*)&hbc, (void*)&dinv2,
                        (void*)&row_ptr, (void*)&ep, (void*)&y04, (void*)&b1,
                        (void*)&W2, (void*)&b2, (void*)&out};
        hipLaunchCooperativeKernel((const void*)k_hops, dim3(NBLK), dim3(256),
                                   args, 0, stream);
    } else {
        const uint2* hin = y0f8c;
        uint2* bufs[2] = {hac, hbc};
        int grid = (N + 31) / 32;
        size_t smemF = (size_t)(H * C + 32 * HSP + C + H) * 4;
        for (int hop = 0; hop < K; ++hop) {
            uint2* hout = bufs[hop & 1];
            if (hop == 0)
                k_prop<true, true, false><<<grid, 256, 0, stream>>>(hin, hout, acch, dinv2,
                    row_ptr, ep, y04, b1, W2, b2, out);
            else if (hop == K - 1)
                k_prop<false, false, true><<<grid, 256, smemF, stream>>>(hin, hout, acch, dinv2,
                    row_ptr, ep, y04, b1, W2, b2, out);
            else
                k_prop<true, false, false><<<grid, 256, 0, stream>>>(hin, hout, acch, dinv2,
                    row_ptr, ep, y04, b1, W2, b2, out);
            hin = hout;
        }
    }
}

// Round 12
// 331.056 us; speedup vs baseline: 1.3109x; 1.0358x over previous
//
#include <hip/hip_runtime.h>
#include <hip/hip_fp16.h>
#include <math.h>

// Problem constants (fixed by the reference)
constexpr int   N   = 50000;
constexpr int   E   = 600000;
constexpr int   FIN = 128;
constexpr int   H   = 64;
constexpr int   C   = 40;
constexpr int   K   = 10;
constexpr float CK  = (1.0f - 0.1f) / 10.0f;  // (1-alpha)/K
constexpr float AL  = 0.1f;                   // alpha

typedef float v2f __attribute__((ext_vector_type(2)));

// pack 4 fp32 -> 4 fp8 e4m3 (HW RNE, OCP on gfx950)
__device__ __forceinline__ unsigned pack_fp8x4(float f0, float f1, float f2, float f3) {
    unsigned r = __builtin_amdgcn_cvt_pk_fp8_f32(f0, f1, 0u, false);
    r = __builtin_amdgcn_cvt_pk_fp8_f32(f2, f3, r, true);
    return r;
}

// 4-byte edge record: low 16 = col (u16, N<=65535), high 16 = fp16 weight
__device__ __forceinline__ float ep_w(unsigned v) {
    return __half2float(__ushort_as_half((unsigned short)(v >> 16)));
}
__device__ __forceinline__ unsigned ep_pack(int c, float w) {
    return (unsigned)(unsigned short)c |
           ((unsigned)__half_as_ushort(__float2half_rn(w)) << 16);
}

// ---------------------------------------------------------------------------
// y0 = x @ W1   (N x 128) @ (128 x 64)
// 64 nodes/block, 256 threads; W1 + padded x rows in LDS; 4x4 register tile.
// ---------------------------------------------------------------------------
constexpr int G1N  = 64;
constexpr int XPAD = 132;
__global__ __launch_bounds__(256, 2) void k_gemm1(const float* __restrict__ x,
                                                  const float* __restrict__ W1,
                                                  float* __restrict__ y0,
                                                  unsigned char* __restrict__ y0f8) {
    __shared__ float ws[FIN * H];
    __shared__ float xs[G1N * XPAD];
    const float4* W14 = (const float4*)W1;
    const float4* x4  = (const float4*)x;
    int t = threadIdx.x;
    int node0 = blockIdx.x * G1N;
    for (int i = t; i < FIN * H / 4; i += 256) ((float4*)ws)[i] = W14[i];
    for (int p = 0; p < 8; ++p) {
        int idx = p * 256 + t;
        int n   = idx >> 5;
        int kk  = idx & 31;
        int node = node0 + n;
        float4 v = (node < N) ? x4[(size_t)node * (FIN / 4) + kk]
                              : make_float4(0.f, 0.f, 0.f, 0.f);
        *(float4*)(xs + n * XPAD + kk * 4) = v;
    }
    __syncthreads();
    int nb = (t >> 4) * 4;
    int cb = (t & 15) * 4;
    float a00=0,a01=0,a02=0,a03=0, a10=0,a11=0,a12=0,a13=0;
    float a20=0,a21=0,a22=0,a23=0, a30=0,a31=0,a32=0,a33=0;
#pragma unroll 8
    for (int k = 0; k < FIN; ++k) {
        float4 wv = *(const float4*)(ws + k * H + cb);
        float x0 = xs[(nb + 0) * XPAD + k];
        float x1 = xs[(nb + 1) * XPAD + k];
        float x2 = xs[(nb + 2) * XPAD + k];
        float x3 = xs[(nb + 3) * XPAD + k];
        a00 = fmaf(x0, wv.x, a00); a01 = fmaf(x0, wv.y, a01);
        a02 = fmaf(x0, wv.z, a02); a03 = fmaf(x0, wv.w, a03);
        a10 = fmaf(x1, wv.x, a10); a11 = fmaf(x1, wv.y, a11);
        a12 = fmaf(x1, wv.z, a12); a13 = fmaf(x1, wv.w, a13);
        a20 = fmaf(x2, wv.x, a20); a21 = fmaf(x2, wv.y, a21);
        a22 = fmaf(x2, wv.z, a22); a23 = fmaf(x2, wv.w, a23);
        a30 = fmaf(x3, wv.x, a30); a31 = fmaf(x3, wv.y, a31);
        a32 = fmaf(x3, wv.z, a32); a33 = fmaf(x3, wv.w, a33);
    }
    float4 rows[4] = {make_float4(a00,a01,a02,a03), make_float4(a10,a11,a12,a13),
                      make_float4(a20,a21,a22,a23), make_float4(a30,a31,a32,a33)};
#pragma unroll
    for (int i = 0; i < 4; ++i) {
        int node = node0 + nb + i;
        if (node >= N) break;
        float4 r = rows[i];
        *(float4*)(y0 + (size_t)node * H + cb) = r;
        *(unsigned*)(y0f8 + (size_t)node * H + cb) = pack_fp8x4(r.x, r.y, r.z, r.w);
    }
}

// ---------------------------------------------------------------------------
// Per-row edge count, 8-way privatized (blockIdx&7 -> XCD-local atomics)
// ---------------------------------------------------------------------------
__global__ void k_count(const int* __restrict__ row, int* __restrict__ cnt8) {
    int e = blockIdx.x * blockDim.x + threadIdx.x;
    if (e >= E) return;
    atomicAdd(&cnt8[(size_t)(blockIdx.x & 7) * N + row[e]], 1);
}

// ---------------------------------------------------------------------------
// Two-level exclusive scan of summed cnt8 -> row_ptr[]
// ---------------------------------------------------------------------------
__global__ __launch_bounds__(1024) void k_scan_blocks(const int* __restrict__ cnt8,
                                                      int* __restrict__ row_ptr,
                                                      int* __restrict__ bsum) {
    __shared__ int s[1024];
    int gid = blockIdx.x * 1024 + threadIdx.x;
    int v = 0;
    if (gid < N) {
#pragma unroll
        for (int c = 0; c < 8; ++c) v += cnt8[(size_t)c * N + gid];
    }
    s[threadIdx.x] = v;
    __syncthreads();
    for (int off = 1; off < 1024; off <<= 1) {
        int t = (threadIdx.x >= off) ? s[threadIdx.x - off] : 0;
        __syncthreads();
        s[threadIdx.x] += t;
        __syncthreads();
    }
    if (gid < N) row_ptr[gid] = s[threadIdx.x] - v;  // exclusive
    if (threadIdx.x == 1023) bsum[blockIdx.x] = s[1023];
}

__global__ void k_scan_sums(const int* __restrict__ bsum, int* __restrict__ boff, int nb) {
    int lane = threadIdx.x;
    int orig = (lane < nb) ? bsum[lane] : 0;
    int v = orig;
    for (int off = 1; off < 64; off <<= 1) {
        int t = __shfl_up(v, off, 64);
        if (lane >= off) v += t;
    }
    if (lane < nb) boff[lane] = v - orig;
}

// Add block offsets AND convert cnt8 copies into per-copy scatter bases
__global__ __launch_bounds__(1024) void k_addoff(int* __restrict__ row_ptr,
                                                 const int* __restrict__ boff,
                                                 int* __restrict__ cnt8) {
    int gid = blockIdx.x * 1024 + threadIdx.x;
    if (gid < N) {
        int rp = row_ptr[gid] + boff[blockIdx.x];
        row_ptr[gid] = rp;
        int off = rp;
#pragma unroll
        for (int c = 0; c < 8; ++c) {
            int t = cnt8[(size_t)c * N + gid];
            cnt8[(size_t)c * N + gid] = off;
            off += t;
        }
    }
    if (gid == 0) row_ptr[N] = E;
}

// ---------------------------------------------------------------------------
// Scatter edges into CSR (4 B records); atomics within XCD-private copy
// ---------------------------------------------------------------------------
__global__ void k_scatter(const int* __restrict__ row, const int* __restrict__ col,
                          const float* __restrict__ w,
                          int* __restrict__ off8, unsigned* __restrict__ ep) {
    int e = blockIdx.x * blockDim.x + threadIdx.x;
    if (e >= E) return;
    int r = row[e];
    int p = atomicAdd(&off8[(size_t)(blockIdx.x & 7) * N + r], 1);
    ep[p] = ep_pack(col[e], w[e]);
}

// ---------------------------------------------------------------------------
// Weighted degree from CSR rows + dinv/dinv2
// ---------------------------------------------------------------------------
__global__ void k_deg_dinv(const unsigned* __restrict__ ep, const int* __restrict__ row_ptr,
                           float* __restrict__ dinv, float* __restrict__ dinv2) {
    int i = blockIdx.x * blockDim.x + threadIdx.x;
    if (i >= N) return;
    float d = 1.0f;   // self-loop weight
    int e0 = row_ptr[i], e1 = row_ptr[i + 1];
    for (int j = e0; j < e1; ++j) d += ep_w(ep[j]);
    float di = rsqrtf(d);
    dinv[i]  = di;
    dinv2[i] = di * di;
}

// ---------------------------------------------------------------------------
// Normalize edge weights in place: w <- dinv[r]*w*dinv[c]
// ---------------------------------------------------------------------------
__global__ __launch_bounds__(256) void k_norm(unsigned* __restrict__ ep,
                                              const int* __restrict__ row_ptr,
                                              const float* __restrict__ dinv) {
    int node = blockIdx.x * 32 + (threadIdx.x >> 3);
    if (node >= N) return;
    int l = threadIdx.x & 7;
    float dr = dinv[node];
    int e0 = row_ptr[node], e1 = row_ptr[node + 1];
    for (int j = e0 + l; j < e1; j += 8) {
        unsigned v = ep[j];
        int c = v & 0xFFFFu;
        ep[j] = ep_pack(c, ep_w(v) * dr * dinv[c]);
    }
}

// ---------------------------------------------------------------------------
// One propagation hop, fp8 h storage (64 B row), 4 B edge records.
// 8 nodes/wave (lane = node-sub x feature-octet), 2 edges in flight.
// 32 nodes/block. acc fp16 in global. FINAL fuses the MLP epilogue.
// ---------------------------------------------------------------------------
constexpr int HSP = 68;
template <bool WRITE_H, bool ACC_INIT, bool FINAL>
__global__ __launch_bounds__(256) void k_prop(const uint2* __restrict__ hin,   // N x 8 (fp8x8)
                                              uint2* __restrict__ hout,
                                              __half* __restrict__ acch,       // N x H fp16
                                              const float* __restrict__ dinv2,
                                              const int* __restrict__ row_ptr,
                                              const unsigned* __restrict__ ep,
                                              const float4* __restrict__ y04,
                                              const float* __restrict__ b1,
                                              const float* __restrict__ W2,
                                              const float* __restrict__ b2,
                                              float* __restrict__ out) {
    extern __shared__ float smem[];          // FINAL only: w2s | hs | b2s | b1s
    float* w2s = smem;
    float* hs  = smem + H * C;
    float* b2s = hs + 32 * HSP;
    float* b1s = b2s + C;
    int t = threadIdx.x;
    if (FINAL) {
        for (int i = t; i < H * C; i += 256) w2s[i] = W2[i];
        if (t < C) b2s[t] = b2[t];
        if (t < H) b1s[t] = b1[t];
        __syncthreads();
    }
    int lane = t & 63;
    int nib  = (t >> 6) * 8 + (lane >> 3);   // node-in-block 0..31
    int l    = lane & 7;                     // feature octet
    int node = blockIdx.x * 32 + nib;
    bool nv  = node < N;
    int nodec = nv ? node : N - 1;
    int start = row_ptr[nodec];
    int deg   = nv ? (row_ptr[nodec + 1] - start) : 0;
    int md = deg;
#pragma unroll
    for (int off = 8; off <= 32; off <<= 1) md = max(md, __shfl_xor(md, off, 64));
    float s[8];
#pragma unroll
    for (int i = 0; i < 8; ++i) s[i] = 0.f;
    auto accum = [&](uint2 v, float w) {
        v2f p0 = __builtin_amdgcn_cvt_pk_f32_fp8(v.x, false);
        v2f p1 = __builtin_amdgcn_cvt_pk_f32_fp8(v.x, true);
        v2f p2 = __builtin_amdgcn_cvt_pk_f32_fp8(v.y, false);
        v2f p3 = __builtin_amdgcn_cvt_pk_f32_fp8(v.y, true);
        s[0] = fmaf(w, p0.x, s[0]); s[1] = fmaf(w, p0.y, s[1]);
        s[2] = fmaf(w, p1.x, s[2]); s[3] = fmaf(w, p1.y, s[3]);
        s[4] = fmaf(w, p2.x, s[4]); s[5] = fmaf(w, p2.y, s[5]);
        s[6] = fmaf(w, p3.x, s[6]); s[7] = fmaf(w, p3.y, s[7]);
    };
    for (int j = 0; j < md; j += 2) {
        bool a0 = j < deg, a1 = j + 1 < deg;
        unsigned e0 = ep[a0 ? start + j     : 0];
        unsigned e1 = ep[a1 ? start + j + 1 : 0];
        uint2 v0 = hin[(size_t)(e0 & 0xFFFFu) * 8 + l];
        uint2 v1 = hin[(size_t)(e1 & 0xFFFFu) * 8 + l];
        float w0 = a0 ? ep_w(e0) : 0.0f;
        float w1 = a1 ? ep_w(e1) : 0.0f;
        accum(v0, w0);
        accum(v1, w1);
    }
    if (nv) {
        size_t base = (size_t)nodec * 8 + l;
        accum(hin[base], dinv2[nodec]);      // self-loop term
        if (WRITE_H) {
            uint2 o;
            o.x = pack_fp8x4(s[0], s[1], s[2], s[3]);
            o.y = pack_fp8x4(s[4], s[5], s[6], s[7]);
            hout[base] = o;
        }
        uint4* ap = (uint4*)(acch + (size_t)nodec * H + l * 8);
        if (FINAL) {
            uint4 old = *ap;
            const unsigned* u = (const unsigned*)&old;
#pragma unroll
            for (int d = 0; d < 4; ++d) {
                float2 f = __half22float2(*(__half2*)&u[d]);
                s[2*d+0] += f.x; s[2*d+1] += f.y;
            }
            float4 ya = y04[(size_t)nodec * (H / 4) + 2 * l];
            float4 yb = y04[(size_t)nodec * (H / 4) + 2 * l + 1];
            const float* bp = b1s + l * 8;
            float* hp = hs + nib * HSP + l * 8;
            hp[0] = fmaxf(fmaf(CK, s[0], fmaf(AL, ya.x, bp[0])), 0.f);
            hp[1] = fmaxf(fmaf(CK, s[1], fmaf(AL, ya.y, bp[1])), 0.f);
            hp[2] = fmaxf(fmaf(CK, s[2], fmaf(AL, ya.z, bp[2])), 0.f);
            hp[3] = fmaxf(fmaf(CK, s[3], fmaf(AL, ya.w, bp[3])), 0.f);
            hp[4] = fmaxf(fmaf(CK, s[4], fmaf(AL, yb.x, bp[4])), 0.f);
            hp[5] = fmaxf(fmaf(CK, s[5], fmaf(AL, yb.y, bp[5])), 0.f);
            hp[6] = fmaxf(fmaf(CK, s[6], fmaf(AL, yb.z, bp[6])), 0.f);
            hp[7] = fmaxf(fmaf(CK, s[7], fmaf(AL, yb.w, bp[7])), 0.f);
        } else {
            if (!ACC_INIT) {
                uint4 old = *ap;
                const unsigned* u = (const unsigned*)&old;
#pragma unroll
                for (int d = 0; d < 4; ++d) {
                    float2 f = __half22float2(*(__half2*)&u[d]);
                    s[2*d+0] += f.x; s[2*d+1] += f.y;
                }
            }
            uint4 nvp;
            unsigned* u = (unsigned*)&nvp;
#pragma unroll
            for (int d = 0; d < 4; ++d) {
                __half2 h = __floats2half2_rn(s[2*d+0], s[2*d+1]);
                u[d] = *(unsigned*)&h;
            }
            *ap = nvp;
        }
    }
    if (FINAL) {
        __syncthreads();
        int node0 = blockIdx.x * 32;
        for (int o = t; o < 32 * C; o += 256) {
            int nl = o / C, c = o % C;
            int n2 = node0 + nl;
            if (n2 >= N) continue;
            float v = b2s[c];
            const float* hr = &hs[nl * HSP];
#pragma unroll
            for (int k = 0; k < H; ++k) v = fmaf(hr[k], w2s[k * C + c], v);
            out[n2 * C + c] = v;
        }
    }
}

// ---------------------------------------------------------------------------
extern "C" void kernel_launch(void* const* d_in, const int* in_sizes, int n_in,
                              void* d_out, int out_size, void* d_ws, size_t ws_size,
                              hipStream_t stream) {
    const float* x  = (const float*)d_in[0];
    const int*   ei = (const int*)d_in[1];
    const float* ew = (const float*)d_in[2];
    const float* W1 = (const float*)d_in[3];
    const float* b1 = (const float*)d_in[4];
    const float* W2 = (const float*)d_in[5];
    const float* b2 = (const float*)d_in[6];
    float* out = (float*)d_out;

    const int* row = ei;
    const int* col = ei + E;

    char* ws = (char*)d_ws;
    size_t off = 0;
    auto alloc = [&](size_t bytes) -> char* {
        char* p = ws + off;
        off = (off + bytes + 1023) & ~(size_t)1023;
        return p;
    };
    float*         y0   = (float*)alloc((size_t)N * H * 4);
    unsigned char* y0f8 = (unsigned char*)alloc((size_t)N * H);
    unsigned char* ha   = (unsigned char*)alloc((size_t)N * H);
    unsigned char* hb   = (unsigned char*)alloc((size_t)N * H);
    __half*        acch = (__half*)alloc((size_t)N * H * 2);
    int*      cnt8   = (int*)     alloc((size_t)8 * N * 4);  // zeroed
    float*    dinv   = (float*)   alloc((size_t)N * 4);
    float*    dinv2  = (float*)   alloc((size_t)N * 4);
    int*      row_ptr= (int*)     alloc((size_t)(N + 1) * 4);
    int*      bsum   = (int*)     alloc(64 * 4);
    int*      boff   = (int*)     alloc(64 * 4);
    unsigned* ep     = (unsigned*)alloc((size_t)E * 4);

    hipMemsetAsync(cnt8, 0, (size_t)8 * N * 4, stream);

    // 1) y0 = x @ W1 (fp32 + fp8)
    k_gemm1<<<(N + G1N - 1) / G1N, 256, 0, stream>>>(x, W1, y0, y0f8);

    // 2) per-row edge counts (XCD-privatized)
    k_count<<<(E + 255) / 256, 256, 0, stream>>>(row, cnt8);

    // 3) scan -> row_ptr; per-copy scatter bases (fused)
    constexpr int NB = (N + 1023) / 1024;  // 49
    k_scan_blocks<<<NB, 1024, 0, stream>>>(cnt8, row_ptr, bsum);
    k_scan_sums<<<1, 64, 0, stream>>>(bsum, boff, NB);
    k_addoff<<<NB, 1024, 0, stream>>>(row_ptr, boff, cnt8);

    // 4) scatter (4 B records), weighted degree + dinv, normalize
    k_scatter<<<(E + 255) / 256, 256, 0, stream>>>(row, col, ew, cnt8, ep);
    k_deg_dinv<<<(N + 255) / 256, 256, 0, stream>>>(ep, row_ptr, dinv, dinv2);
    k_norm<<<(N + 31) / 32, 256, 0, stream>>>(ep, row_ptr, dinv);

    // 5) K hops; hop 0 inits acc, hop K-1 fuses the MLP epilogue
    const uint2* hin = (const uint2*)y0f8;
    uint2* bufs[2] = {(uint2*)ha, (uint2*)hb};
    const float4* y04 = (const float4*)y0;
    int grid = (N + 31) / 32;
    size_t smemF = (size_t)(H * C + 32 * HSP + C + H) * 4;
    for (int hop = 0; hop < K; ++hop) {
        uint2* hout = bufs[hop & 1];
        if (hop == 0)
            k_prop<true, true, false><<<grid, 256, 0, stream>>>(hin, hout, acch, dinv2,
                row_ptr, ep, y04, b1, W2, b2, out);
        else if (hop == K - 1)
            k_prop<false, false, true><<<grid, 256, smemF, stream>>>(hin, hout, acch, dinv2,
                row_ptr, ep, y04, b1, W2, b2, out);
        else
            k_prop<true, false, false><<<grid, 256, 0, stream>>>(hin, hout, acch, dinv2,
                row_ptr, ep, y04, b1, W2, b2, out);
        hin = hout;
    }
}